// Round 1
// baseline (1168.427 us; speedup 1.0000x reference)
//
#include <hip/hip_runtime.h>
#include <hip/hip_bf16.h>
#include <math.h>

#define B_ 4
#define S_ 2048
#define D_ 512
#define H_ 8
#define HD_ 64
#define DFF_ 1024
#define EPS_ 1e-5f

// =================================================================
// GEMM: C = epi(A @ W^T + bias)
// A [M,K] row-major, W [N,K] row-major.
// EPI 0: C[M,N] plain   EPI 1: relu   EPI 2: scatter to [B,H,S,HD] (N==512)
// Tile 128x128, BK=16, 256 threads, 8x8 accum/thread (two 4-wide quadrants).
// =================================================================
template<int EPI>
__global__ __launch_bounds__(256)
void gemm_tn(const float* __restrict__ A, const float* __restrict__ W,
             const float* __restrict__ bias, float* __restrict__ C,
             int M, int N, int K) {
    // stride 132 (== 4 mod 32 banks): staging writes 2-way, frag reads 2-way max
    __shared__ float As[16][132];
    __shared__ float Ws[16][132];
    const int tid = threadIdx.x;
    const int tx = tid & 15, ty = tid >> 4;
    const int bm = blockIdx.x * 128;
    const int bn = blockIdx.y * 128;
    const int lr = tid >> 2;         // 0..63 tile row for staging
    const int lc = (tid & 3) << 2;   // k-chunk 0,4,8,12

    float acc[8][8];
#pragma unroll
    for (int i = 0; i < 8; ++i)
#pragma unroll
        for (int j = 0; j < 8; ++j) acc[i][j] = 0.f;

    for (int k0 = 0; k0 < K; k0 += 16) {
        float4 av0 = *(const float4*)(A + (size_t)(bm + lr) * K + k0 + lc);
        float4 av1 = *(const float4*)(A + (size_t)(bm + lr + 64) * K + k0 + lc);
        float4 wv0 = *(const float4*)(W + (size_t)(bn + lr) * K + k0 + lc);
        float4 wv1 = *(const float4*)(W + (size_t)(bn + lr + 64) * K + k0 + lc);
        __syncthreads();
        As[lc + 0][lr] = av0.x; As[lc + 1][lr] = av0.y;
        As[lc + 2][lr] = av0.z; As[lc + 3][lr] = av0.w;
        As[lc + 0][lr + 64] = av1.x; As[lc + 1][lr + 64] = av1.y;
        As[lc + 2][lr + 64] = av1.z; As[lc + 3][lr + 64] = av1.w;
        Ws[lc + 0][lr] = wv0.x; Ws[lc + 1][lr] = wv0.y;
        Ws[lc + 2][lr] = wv0.z; Ws[lc + 3][lr] = wv0.w;
        Ws[lc + 0][lr + 64] = wv1.x; Ws[lc + 1][lr + 64] = wv1.y;
        Ws[lc + 2][lr + 64] = wv1.z; Ws[lc + 3][lr + 64] = wv1.w;
        __syncthreads();
#pragma unroll
        for (int k = 0; k < 16; ++k) {
            float ar[8], br[8];
            float4 t;
            t = *(const float4*)&As[k][ty * 4];      ar[0]=t.x; ar[1]=t.y; ar[2]=t.z; ar[3]=t.w;
            t = *(const float4*)&As[k][64 + ty * 4]; ar[4]=t.x; ar[5]=t.y; ar[6]=t.z; ar[7]=t.w;
            t = *(const float4*)&Ws[k][tx * 4];      br[0]=t.x; br[1]=t.y; br[2]=t.z; br[3]=t.w;
            t = *(const float4*)&Ws[k][64 + tx * 4]; br[4]=t.x; br[5]=t.y; br[6]=t.z; br[7]=t.w;
#pragma unroll
            for (int i = 0; i < 8; ++i)
#pragma unroll
                for (int j = 0; j < 8; ++j)
                    acc[i][j] = fmaf(ar[i], br[j], acc[i][j]);
        }
    }
    // epilogue
    float4 bi0 = *(const float4*)(bias + bn + tx * 4);
    float4 bi1 = *(const float4*)(bias + bn + 64 + tx * 4);
    float bv[8] = {bi0.x, bi0.y, bi0.z, bi0.w, bi1.x, bi1.y, bi1.z, bi1.w};
#pragma unroll
    for (int i = 0; i < 8; ++i) {
        int gr = bm + ((i < 4) ? (ty * 4 + i) : (64 + ty * 4 + (i - 4)));
#pragma unroll
        for (int q = 0; q < 2; ++q) {
            int gc = bn + q * 64 + tx * 4;
            float4 v;
            v.x = acc[i][q * 4 + 0] + bv[q * 4 + 0];
            v.y = acc[i][q * 4 + 1] + bv[q * 4 + 1];
            v.z = acc[i][q * 4 + 2] + bv[q * 4 + 2];
            v.w = acc[i][q * 4 + 3] + bv[q * 4 + 3];
            if (EPI == 1) {
                v.x = fmaxf(v.x, 0.f); v.y = fmaxf(v.y, 0.f);
                v.z = fmaxf(v.z, 0.f); v.w = fmaxf(v.w, 0.f);
            }
            if (EPI == 2) {
                int bb = gr >> 11, ss = gr & (S_ - 1);
                int hh = gc >> 6, hd = gc & 63;
                *(float4*)(C + (((size_t)bb * H_ + hh) * S_ + ss) * HD_ + hd) = v;
            } else {
                *(float4*)(C + (size_t)gr * N + gc) = v;
            }
        }
    }
}

// =================================================================
// Flash attention fp32: Q,K,V [B,H,S,HD] -> AV [B,S,D]
// Block: 256 thr, 64 queries; iterate 64-key tiles; online softmax.
// =================================================================
__global__ __launch_bounds__(256)
void attn_fwd(const float* __restrict__ Qg, const float* __restrict__ Kg,
              const float* __restrict__ Vg, float* __restrict__ AV) {
    __shared__ float Qt[64 * 68];   // [hd][q], pre-scaled by 1/8
    __shared__ float KtP[64 * 68];  // [hd][k] for scores; reused as P [q][k]
    __shared__ float Vs[64 * 68];   // [k][hd]
    const int tid = threadIdx.x;
    const int tx = tid & 15, ty = tid >> 4;
    const int qb = blockIdx.x;      // S/64 = 32
    const int bh = blockIdx.y;      // B*H = 32
    const int b = bh >> 3, h = bh & 7;
    const float* Qp = Qg + (((size_t)bh) * S_ + qb * 64) * HD_;
    const float* Kp = Kg + ((size_t)bh) * S_ * HD_;
    const float* Vp = Vg + ((size_t)bh) * S_ * HD_;

    // stage Q transposed + scaled: lane pattern r=tid&63, chunk=tid>>6
    {
        const int r = tid & 63, c0 = (tid >> 6) * 16;
        const float* src = Qp + r * HD_ + c0;
        float vals[16];
        *(float4*)&vals[0]  = *(const float4*)(src + 0);
        *(float4*)&vals[4]  = *(const float4*)(src + 4);
        *(float4*)&vals[8]  = *(const float4*)(src + 8);
        *(float4*)&vals[12] = *(const float4*)(src + 12);
#pragma unroll
        for (int e = 0; e < 16; ++e) Qt[(c0 + e) * 68 + r] = vals[e] * 0.125f;
    }

    float m_[4], l_[4], o_[4][4];
#pragma unroll
    for (int i = 0; i < 4; ++i) {
        m_[i] = -INFINITY; l_[i] = 0.f;
#pragma unroll
        for (int j = 0; j < 4; ++j) o_[i][j] = 0.f;
    }

    for (int kt = 0; kt < S_ / 64; ++kt) {
        __syncthreads();  // protect Qt (iter 0) / P,Vs from previous iter
        {   // stage K transposed
            const int r = tid & 63, c0 = (tid >> 6) * 16;
            const float* src = Kp + ((size_t)(kt * 64 + r)) * HD_ + c0;
            float vals[16];
            *(float4*)&vals[0]  = *(const float4*)(src + 0);
            *(float4*)&vals[4]  = *(const float4*)(src + 4);
            *(float4*)&vals[8]  = *(const float4*)(src + 8);
            *(float4*)&vals[12] = *(const float4*)(src + 12);
#pragma unroll
            for (int e = 0; e < 16; ++e) KtP[(c0 + e) * 68 + r] = vals[e];
        }
        {   // stage V natural [k][hd]
            const int r = tid >> 2, cc = (tid & 3) * 16;
            const float* src = Vp + ((size_t)(kt * 64 + r)) * HD_ + cc;
            float4 v0 = *(const float4*)(src + 0);
            float4 v1 = *(const float4*)(src + 4);
            float4 v2 = *(const float4*)(src + 8);
            float4 v3 = *(const float4*)(src + 12);
            *(float4*)&Vs[r * 68 + cc + 0]  = v0;
            *(float4*)&Vs[r * 68 + cc + 4]  = v1;
            *(float4*)&Vs[r * 68 + cc + 8]  = v2;
            *(float4*)&Vs[r * 68 + cc + 12] = v3;
        }
        __syncthreads();
        // scores S = Q^T-tiles @ K-tiles (per-thread 4q x 4k)
        float s_[4][4];
#pragma unroll
        for (int i = 0; i < 4; ++i)
#pragma unroll
            for (int j = 0; j < 4; ++j) s_[i][j] = 0.f;
#pragma unroll 16
        for (int k = 0; k < 64; ++k) {
            float4 a = *(const float4*)&Qt[k * 68 + ty * 4];
            float4 bb = *(const float4*)&KtP[k * 68 + tx * 4];
            float ar[4] = {a.x, a.y, a.z, a.w};
            float br[4] = {bb.x, bb.y, bb.z, bb.w};
#pragma unroll
            for (int i = 0; i < 4; ++i)
#pragma unroll
                for (int j = 0; j < 4; ++j)
                    s_[i][j] = fmaf(ar[i], br[j], s_[i][j]);
        }
        __syncthreads();  // done reading K before overwriting KtP with P
        // online softmax update (row stats across 16-lane tx group)
#pragma unroll
        for (int i = 0; i < 4; ++i) {
            float mloc = fmaxf(fmaxf(s_[i][0], s_[i][1]), fmaxf(s_[i][2], s_[i][3]));
            for (int d = 1; d < 16; d <<= 1) mloc = fmaxf(mloc, __shfl_xor(mloc, d));
            float mc = fmaxf(m_[i], mloc);
            float al = (m_[i] == -INFINITY) ? 0.f : __expf(m_[i] - mc);
            float ps = 0.f;
#pragma unroll
            for (int j = 0; j < 4; ++j) {
                float p = __expf(s_[i][j] - mc);
                KtP[(ty * 4 + i) * 68 + tx * 4 + j] = p;
                ps += p;
            }
            for (int d = 1; d < 16; d <<= 1) ps += __shfl_xor(ps, d);
            l_[i] = l_[i] * al + ps;
            m_[i] = mc;
#pragma unroll
            for (int j = 0; j < 4; ++j) o_[i][j] *= al;
        }
        __syncthreads();  // P visible to all
        // PV: o += P @ V   (per-thread 4q x 4hd)
#pragma unroll 16
        for (int kk = 0; kk < 64; ++kk) {
            float4 bb = *(const float4*)&Vs[kk * 68 + tx * 4];
            float br[4] = {bb.x, bb.y, bb.z, bb.w};
            float ar[4];
#pragma unroll
            for (int i = 0; i < 4; ++i) ar[i] = KtP[(ty * 4 + i) * 68 + kk];
#pragma unroll
            for (int i = 0; i < 4; ++i)
#pragma unroll
                for (int j = 0; j < 4; ++j)
                    o_[i][j] = fmaf(ar[i], br[j], o_[i][j]);
        }
    }
    // epilogue: divide by l, write av[b][s][h*64+hd]
#pragma unroll
    for (int i = 0; i < 4; ++i) {
        float inv = 1.0f / l_[i];
        int srow = qb * 64 + ty * 4 + i;
        float4 v;
        v.x = o_[i][0] * inv; v.y = o_[i][1] * inv;
        v.z = o_[i][2] * inv; v.w = o_[i][3] * inv;
        *(float4*)(AV + ((size_t)b * S_ + srow) * D_ + h * HD_ + tx * 4) = v;
    }
}

// =================================================================
// y = LayerNorm(x + r) * g + be ; one wave per 512-wide row
// =================================================================
__global__ __launch_bounds__(256)
void add_ln(const float* __restrict__ X, const float* __restrict__ R,
            const float* __restrict__ g, const float* __restrict__ be,
            float* __restrict__ Y) {
    const int row = blockIdx.x * 4 + (threadIdx.x >> 6);
    const int lane = threadIdx.x & 63;
    const float4* xp = (const float4*)(X + (size_t)row * D_);
    const float4* rp = (const float4*)(R + (size_t)row * D_);
    float4 v0 = xp[lane], v1 = xp[lane + 64];
    float4 r0 = rp[lane], r1 = rp[lane + 64];
    v0.x += r0.x; v0.y += r0.y; v0.z += r0.z; v0.w += r0.w;
    v1.x += r1.x; v1.y += r1.y; v1.z += r1.z; v1.w += r1.w;
    float sum = v0.x + v0.y + v0.z + v0.w + v1.x + v1.y + v1.z + v1.w;
    for (int d = 1; d < 64; d <<= 1) sum += __shfl_xor(sum, d);
    const float mu = sum * (1.0f / D_);
    float s2 = (v0.x - mu) * (v0.x - mu) + (v0.y - mu) * (v0.y - mu) +
               (v0.z - mu) * (v0.z - mu) + (v0.w - mu) * (v0.w - mu) +
               (v1.x - mu) * (v1.x - mu) + (v1.y - mu) * (v1.y - mu) +
               (v1.z - mu) * (v1.z - mu) + (v1.w - mu) * (v1.w - mu);
    for (int d = 1; d < 64; d <<= 1) s2 += __shfl_xor(s2, d);
    const float rs = rsqrtf(s2 * (1.0f / D_) + EPS_);
    float4 g0 = ((const float4*)g)[lane], g1v = ((const float4*)g)[lane + 64];
    float4 b0 = ((const float4*)be)[lane], b1v = ((const float4*)be)[lane + 64];
    float4 o0, o1;
    o0.x = (v0.x - mu) * rs * g0.x + b0.x;
    o0.y = (v0.y - mu) * rs * g0.y + b0.y;
    o0.z = (v0.z - mu) * rs * g0.z + b0.z;
    o0.w = (v0.w - mu) * rs * g0.w + b0.w;
    o1.x = (v1.x - mu) * rs * g1v.x + b1v.x;
    o1.y = (v1.y - mu) * rs * g1v.y + b1v.y;
    o1.z = (v1.z - mu) * rs * g1v.z + b1v.z;
    o1.w = (v1.w - mu) * rs * g1v.w + b1v.w;
    ((float4*)(Y + (size_t)row * D_))[lane] = o0;
    ((float4*)(Y + (size_t)row * D_))[lane + 64] = o1;
}

// =================================================================
extern "C" void kernel_launch(void* const* d_in, const int* in_sizes, int n_in,
                              void* d_out, int out_size, void* d_ws, size_t ws_size,
                              hipStream_t stream) {
    const float* x   = (const float*)d_in[0];
    const float* wq  = (const float*)d_in[1];
    const float* bq  = (const float*)d_in[2];
    const float* wk  = (const float*)d_in[3];
    const float* bk  = (const float*)d_in[4];
    const float* wv  = (const float*)d_in[5];
    const float* bv  = (const float*)d_in[6];
    const float* wo  = (const float*)d_in[7];
    const float* bo  = (const float*)d_in[8];
    const float* w1  = (const float*)d_in[9];
    const float* b1  = (const float*)d_in[10];
    const float* w2  = (const float*)d_in[11];
    const float* b2  = (const float*)d_in[12];
    const float* g1  = (const float*)d_in[13];
    const float* be1 = (const float*)d_in[14];
    const float* g2  = (const float*)d_in[15];
    const float* be2 = (const float*)d_in[16];

    float* ws = (float*)d_ws;
    const size_t SZ = (size_t)B_ * S_ * D_;  // 4,194,304 floats
    float* q  = ws;            // [B,H,S,HD]
    float* k  = ws + SZ;
    float* v  = ws + 2 * SZ;
    float* av = ws + 3 * SZ;   // [B,S,D]
    float* ao = ws;            // reuse q (dead after attn)
    float* x1 = ws + SZ;       // reuse k
    float* hh = ws + 2 * SZ;   // reuse v..av (DFF=2*D, spans 2 slots)
    float* ff = ws;            // reuse ao

    const int M = B_ * S_;     // 8192
    dim3 blk(256);

    // QKV projections, scattered to [B,H,S,HD]
    gemm_tn<2><<<dim3(M / 128, D_ / 128), blk, 0, stream>>>(x, wq, bq, q, M, D_, D_);
    gemm_tn<2><<<dim3(M / 128, D_ / 128), blk, 0, stream>>>(x, wk, bk, k, M, D_, D_);
    gemm_tn<2><<<dim3(M / 128, D_ / 128), blk, 0, stream>>>(x, wv, bv, v, M, D_, D_);
    // attention
    attn_fwd<<<dim3(S_ / 64, B_ * H_), blk, 0, stream>>>(q, k, v, av);
    // output projection
    gemm_tn<0><<<dim3(M / 128, D_ / 128), blk, 0, stream>>>(av, wo, bo, ao, M, D_, D_);
    // residual + LN1
    add_ln<<<dim3(M / 4), blk, 0, stream>>>(x, ao, g1, be1, x1);
    // FFN
    gemm_tn<1><<<dim3(M / 128, DFF_ / 128), blk, 0, stream>>>(x1, w1, b1, hh, M, DFF_, D_);
    gemm_tn<0><<<dim3(M / 128, D_ / 128), blk, 0, stream>>>(hh, w2, b2, ff, M, D_, DFF_);
    // residual + LN2 -> out
    add_ln<<<dim3(M / 4), blk, 0, stream>>>(x1, ff, g2, be2, (float*)d_out);
}

// Round 2
// 873.746 us; speedup vs baseline: 1.3373x; 1.3373x over previous
//
#include <hip/hip_runtime.h>
#include <math.h>

#define B_ 4
#define S_ 2048
#define D_ 512
#define H_ 8
#define HD_ 64
#define DFF_ 1024
#define EPS_ 1e-5f

typedef __attribute__((ext_vector_type(4))) unsigned short u16x4;
typedef __attribute__((ext_vector_type(8))) unsigned short u16x8;
typedef __attribute__((ext_vector_type(8))) short s16x8;
typedef __attribute__((ext_vector_type(4))) float f32x4;

__device__ __forceinline__ unsigned short f2bf(float f) {
    union { float f; unsigned u; } a; a.f = f;
    unsigned r = a.u + 0x7fffu + ((a.u >> 16) & 1u);   // RNE
    return (unsigned short)(r >> 16);
}
__device__ __forceinline__ float bf2f(unsigned short u) {
    union { unsigned u; float f; } a; a.u = ((unsigned)u) << 16;
    return a.f;
}
__device__ __forceinline__ void mfma_bf16(f32x4& d, s16x8 a, s16x8 b) {
    asm("v_mfma_f32_16x16x32_bf16 %0, %1, %2, %0" : "+v"(d) : "v"(a), "v"(b));
}

#define GLOAD(gp, lp) __builtin_amdgcn_global_load_lds( \
    (const __attribute__((address_space(1))) unsigned int*)(gp), \
    (__attribute__((address_space(3))) unsigned int*)(lp), 16, 0, 0)

// =================================================================
// split fp32 -> (hi bf16, lo bf16)
// =================================================================
__global__ __launch_bounds__(256)
void split_f32(const float4* __restrict__ in, u16x4* __restrict__ oh,
               u16x4* __restrict__ ol, int n4) {
    int i = blockIdx.x * 256 + threadIdx.x;
    if (i >= n4) return;
    float4 v = in[i];
    u16x4 h, l;
    h.x = f2bf(v.x); l.x = f2bf(v.x - bf2f(h.x));
    h.y = f2bf(v.y); l.y = f2bf(v.y - bf2f(h.y));
    h.z = f2bf(v.z); l.z = f2bf(v.z - bf2f(h.z));
    h.w = f2bf(v.w); l.w = f2bf(v.w - bf2f(h.w));
    oh[i] = h; ol[i] = l;
}

// =================================================================
// bf16x3 MFMA GEMM: C = epi((Ah+Al) @ (Wh+Wl)^T + bias)
// A [M,K] row-major split bf16, W [N,K] row-major split bf16.
// 128x128 tile, BK=32, 4 waves, each wave 64x64 (4x4 frags 16x16x32).
// LDS linear [128][32] bf16 per array; XOR swizzle: k-slot stored at
// slot ^ ((row>>1)&3) -> 2-way max bank aliasing on ds_read_b128.
// global_load_lds writes linearly; source address pre-swizzled.
// EPI 0: Cf fp32 [M,N]. EPI 1: relu -> Ch bf16 [M,N].
// EPI 2: split bf16 scatter [B,H,S,HD]. EPI 3: single bf16 scatter.
// =================================================================
template<int EPI, bool ASPLIT>
__global__ __launch_bounds__(256)
void gemm_x3(const unsigned short* __restrict__ Ah, const unsigned short* __restrict__ Al,
             const unsigned short* __restrict__ Wh, const unsigned short* __restrict__ Wl,
             const float* __restrict__ bias,
             float* __restrict__ Cf, unsigned short* __restrict__ Ch,
             unsigned short* __restrict__ Cl, int M, int N, int K) {
    __shared__ __align__(16) unsigned short AhL[4096];
    __shared__ __align__(16) unsigned short AlL[4096];
    __shared__ __align__(16) unsigned short WhL[4096];
    __shared__ __align__(16) unsigned short WlL[4096];
    const int tid = threadIdx.x;
    const int lane = tid & 63;
    const int wid = tid >> 6;
    const int wr = wid >> 1, wc = wid & 1;
    const int bm = blockIdx.x * 128, bn = blockIdx.y * 128;

    // staging: wave-call c covers LDS bytes (wid*2+c)*1024 .. +1024
    const int i0 = wid * 128 + lane, i1 = i0 + 64;
    const int r0 = i0 >> 2, r1 = i1 >> 2;
    const int s0 = (i0 & 3) ^ ((r0 >> 1) & 3);
    const int s1 = (i1 & 3) ^ ((r1 >> 1) & 3);
    const size_t a0 = (size_t)(bm + r0) * K + s0 * 8;
    const size_t a1 = (size_t)(bm + r1) * K + s1 * 8;
    const size_t w0 = (size_t)(bn + r0) * K + s0 * 8;
    const size_t w1 = (size_t)(bn + r1) * K + s1 * 8;
    const int lb0 = (wid * 2 + 0) * 512;   // ushort index
    const int lb1 = (wid * 2 + 1) * 512;

    f32x4 acc[4][4];
#pragma unroll
    for (int m = 0; m < 4; ++m)
#pragma unroll
        for (int n = 0; n < 4; ++n) acc[m][n] = f32x4{0.f, 0.f, 0.f, 0.f};

    const int fr = lane & 15, ks = lane >> 4;
    int offA[4], offW[4];
#pragma unroll
    for (int m = 0; m < 4; ++m) {
        int r = wr * 64 + m * 16 + fr;
        offA[m] = r * 32 + ((ks ^ ((r >> 1) & 3)) * 8);
    }
#pragma unroll
    for (int n = 0; n < 4; ++n) {
        int r = wc * 64 + n * 16 + fr;
        offW[n] = r * 32 + ((ks ^ ((r >> 1) & 3)) * 8);
    }

    for (int k0 = 0; k0 < K; k0 += 32) {
        __syncthreads();
        GLOAD(Ah + a0 + k0, AhL + lb0);
        GLOAD(Ah + a1 + k0, AhL + lb1);
        if (ASPLIT) {
            GLOAD(Al + a0 + k0, AlL + lb0);
            GLOAD(Al + a1 + k0, AlL + lb1);
        }
        GLOAD(Wh + w0 + k0, WhL + lb0);
        GLOAD(Wh + w1 + k0, WhL + lb1);
        GLOAD(Wl + w0 + k0, WlL + lb0);
        GLOAD(Wl + w1 + k0, WlL + lb1);
        __syncthreads();
        s16x8 fah[4], fal[4], fwh[4], fwl[4];
#pragma unroll
        for (int m = 0; m < 4; ++m) {
            fah[m] = *(const s16x8*)&AhL[offA[m]];
            if (ASPLIT) fal[m] = *(const s16x8*)&AlL[offA[m]];
        }
#pragma unroll
        for (int n = 0; n < 4; ++n) {
            fwh[n] = *(const s16x8*)&WhL[offW[n]];
            fwl[n] = *(const s16x8*)&WlL[offW[n]];
        }
#pragma unroll
        for (int m = 0; m < 4; ++m)
#pragma unroll
            for (int n = 0; n < 4; ++n) {
                mfma_bf16(acc[m][n], fah[m], fwh[n]);
                mfma_bf16(acc[m][n], fah[m], fwl[n]);
                if (ASPLIT) mfma_bf16(acc[m][n], fal[m], fwh[n]);
            }
    }

    // epilogue: C row = ks*4 + j (+m*16 + wr*64), col = fr (+n*16 + wc*64)
#pragma unroll
    for (int n = 0; n < 4; ++n) {
        int gc = bn + wc * 64 + n * 16 + fr;
        float bz = bias[gc];
#pragma unroll
        for (int m = 0; m < 4; ++m) {
#pragma unroll
            for (int j = 0; j < 4; ++j) {
                int gr = bm + wr * 64 + m * 16 + ks * 4 + j;
                float val = acc[m][n][j] + bz;
                if (EPI == 0) {
                    Cf[(size_t)gr * N + gc] = val;
                } else if (EPI == 1) {
                    Ch[(size_t)gr * N + gc] = f2bf(fmaxf(val, 0.f));
                } else {
                    int bb = gr >> 11, ss = gr & (S_ - 1);
                    int he = gc >> 6, hd = gc & 63;
                    size_t oi = (((size_t)bb * H_ + he) * S_ + ss) * HD_ + hd;
                    unsigned short h = f2bf(val);
                    Ch[oi] = h;
                    if (EPI == 2) Cl[oi] = f2bf(val - bf2f(h));
                }
            }
        }
    }
}

// =================================================================
// Flash attention fp32 VALU; Q,K split bf16, V single bf16 [B,H,S,HD]
// -> AV split bf16 [B,S,D]
// =================================================================
__global__ __launch_bounds__(256)
void attn_fwd(const unsigned short* __restrict__ Qh, const unsigned short* __restrict__ Ql,
              const unsigned short* __restrict__ Kh, const unsigned short* __restrict__ Kl,
              const unsigned short* __restrict__ Vh,
              unsigned short* __restrict__ AVh, unsigned short* __restrict__ AVl) {
    __shared__ float Qt[64 * 68];   // [hd][q], pre-scaled by 1/8
    __shared__ float KtP[64 * 68];  // [hd][k] for scores; reused as P [q][k]
    __shared__ float Vs[64 * 68];   // [k][hd]
    const int tid = threadIdx.x;
    const int tx = tid & 15, ty = tid >> 4;
    const int qb = blockIdx.x;
    const int bh = blockIdx.y;
    const int b = bh >> 3, h = bh & 7;
    const size_t qoff = (((size_t)bh) * S_ + qb * 64) * HD_;
    const size_t koff = ((size_t)bh) * S_ * HD_;

    {   // stage Q transposed + scaled
        const int r = tid & 63, c0 = (tid >> 6) * 16;
        const unsigned short* sh = Qh + qoff + r * HD_ + c0;
        const unsigned short* sl = Ql + qoff + r * HD_ + c0;
        u16x8 h0 = *(const u16x8*)sh, h1 = *(const u16x8*)(sh + 8);
        u16x8 l0 = *(const u16x8*)sl, l1 = *(const u16x8*)(sl + 8);
#pragma unroll
        for (int e = 0; e < 8; ++e) {
            Qt[(c0 + e) * 68 + r]     = (bf2f(h0[e]) + bf2f(l0[e])) * 0.125f;
            Qt[(c0 + 8 + e) * 68 + r] = (bf2f(h1[e]) + bf2f(l1[e])) * 0.125f;
        }
    }

    float m_[4], l_[4], o_[4][4];
#pragma unroll
    for (int i = 0; i < 4; ++i) {
        m_[i] = -INFINITY; l_[i] = 0.f;
#pragma unroll
        for (int j = 0; j < 4; ++j) o_[i][j] = 0.f;
    }

    for (int kt = 0; kt < S_ / 64; ++kt) {
        __syncthreads();
        {   // stage K transposed (reconstruct hi+lo)
            const int r = tid & 63, c0 = (tid >> 6) * 16;
            const unsigned short* sh = Kh + koff + ((size_t)(kt * 64 + r)) * HD_ + c0;
            const unsigned short* sl = Kl + koff + ((size_t)(kt * 64 + r)) * HD_ + c0;
            u16x8 h0 = *(const u16x8*)sh, h1 = *(const u16x8*)(sh + 8);
            u16x8 l0 = *(const u16x8*)sl, l1 = *(const u16x8*)(sl + 8);
#pragma unroll
            for (int e = 0; e < 8; ++e) {
                KtP[(c0 + e) * 68 + r]     = bf2f(h0[e]) + bf2f(l0[e]);
                KtP[(c0 + 8 + e) * 68 + r] = bf2f(h1[e]) + bf2f(l1[e]);
            }
        }
        {   // stage V natural [k][hd]
            const int r = tid >> 2, cc = (tid & 3) * 16;
            const unsigned short* sv = Vh + koff + ((size_t)(kt * 64 + r)) * HD_ + cc;
            u16x8 v0 = *(const u16x8*)sv, v1 = *(const u16x8*)(sv + 8);
#pragma unroll
            for (int e = 0; e < 8; ++e) {
                Vs[r * 68 + cc + e]     = bf2f(v0[e]);
                Vs[r * 68 + cc + 8 + e] = bf2f(v1[e]);
            }
        }
        __syncthreads();
        float s_[4][4];
#pragma unroll
        for (int i = 0; i < 4; ++i)
#pragma unroll
            for (int j = 0; j < 4; ++j) s_[i][j] = 0.f;
#pragma unroll 16
        for (int k = 0; k < 64; ++k) {
            float4 a = *(const float4*)&Qt[k * 68 + ty * 4];
            float4 bb = *(const float4*)&KtP[k * 68 + tx * 4];
            float ar[4] = {a.x, a.y, a.z, a.w};
            float br[4] = {bb.x, bb.y, bb.z, bb.w};
#pragma unroll
            for (int i = 0; i < 4; ++i)
#pragma unroll
                for (int j = 0; j < 4; ++j)
                    s_[i][j] = fmaf(ar[i], br[j], s_[i][j]);
        }
        __syncthreads();
#pragma unroll
        for (int i = 0; i < 4; ++i) {
            float mloc = fmaxf(fmaxf(s_[i][0], s_[i][1]), fmaxf(s_[i][2], s_[i][3]));
            for (int d = 1; d < 16; d <<= 1) mloc = fmaxf(mloc, __shfl_xor(mloc, d));
            float mc = fmaxf(m_[i], mloc);
            float al = (m_[i] == -INFINITY) ? 0.f : __expf(m_[i] - mc);
            float ps = 0.f;
#pragma unroll
            for (int j = 0; j < 4; ++j) {
                float p = __expf(s_[i][j] - mc);
                KtP[(ty * 4 + i) * 68 + tx * 4 + j] = p;
                ps += p;
            }
            for (int d = 1; d < 16; d <<= 1) ps += __shfl_xor(ps, d);
            l_[i] = l_[i] * al + ps;
            m_[i] = mc;
#pragma unroll
            for (int j = 0; j < 4; ++j) o_[i][j] *= al;
        }
        __syncthreads();
#pragma unroll 16
        for (int kk = 0; kk < 64; ++kk) {
            float4 bb = *(const float4*)&Vs[kk * 68 + tx * 4];
            float br[4] = {bb.x, bb.y, bb.z, bb.w};
            float ar[4];
#pragma unroll
            for (int i = 0; i < 4; ++i) ar[i] = KtP[(ty * 4 + i) * 68 + kk];
#pragma unroll
            for (int i = 0; i < 4; ++i)
#pragma unroll
                for (int j = 0; j < 4; ++j)
                    o_[i][j] = fmaf(ar[i], br[j], o_[i][j]);
        }
    }
    // epilogue: divide by l, split write av[b][s][h*64+hd]
#pragma unroll
    for (int i = 0; i < 4; ++i) {
        float inv = 1.0f / l_[i];
        int srow = qb * 64 + ty * 4 + i;
        size_t oi = ((size_t)b * S_ + srow) * D_ + h * HD_ + tx * 4;
        u16x4 hv, lv;
#pragma unroll
        for (int j = 0; j < 4; ++j) {
            float val = o_[i][j] * inv;
            unsigned short hb = f2bf(val);
            hv[j] = hb;
            lv[j] = f2bf(val - bf2f(hb));
        }
        *(u16x4*)(AVh + oi) = hv;
        *(u16x4*)(AVl + oi) = lv;
    }
}

// =================================================================
// LN1: y = LayerNorm(x + r) -> split bf16 (x1h, x1l)
// =================================================================
__global__ __launch_bounds__(256)
void add_ln_split(const float* __restrict__ X, const float* __restrict__ R,
                  const float* __restrict__ g, const float* __restrict__ be,
                  unsigned short* __restrict__ Yh, unsigned short* __restrict__ Yl) {
    const int row = blockIdx.x * 4 + (threadIdx.x >> 6);
    const int lane = threadIdx.x & 63;
    const float4* xp = (const float4*)(X + (size_t)row * D_);
    const float4* rp = (const float4*)(R + (size_t)row * D_);
    float4 v0 = xp[lane], v1 = xp[lane + 64];
    float4 r0 = rp[lane], r1 = rp[lane + 64];
    v0.x += r0.x; v0.y += r0.y; v0.z += r0.z; v0.w += r0.w;
    v1.x += r1.x; v1.y += r1.y; v1.z += r1.z; v1.w += r1.w;
    float sum = v0.x + v0.y + v0.z + v0.w + v1.x + v1.y + v1.z + v1.w;
    for (int d = 1; d < 64; d <<= 1) sum += __shfl_xor(sum, d);
    const float mu = sum * (1.0f / D_);
    float s2 = (v0.x - mu) * (v0.x - mu) + (v0.y - mu) * (v0.y - mu) +
               (v0.z - mu) * (v0.z - mu) + (v0.w - mu) * (v0.w - mu) +
               (v1.x - mu) * (v1.x - mu) + (v1.y - mu) * (v1.y - mu) +
               (v1.z - mu) * (v1.z - mu) + (v1.w - mu) * (v1.w - mu);
    for (int d = 1; d < 64; d <<= 1) s2 += __shfl_xor(s2, d);
    const float rs = rsqrtf(s2 * (1.0f / D_) + EPS_);
    float4 g0 = ((const float4*)g)[lane], g1v = ((const float4*)g)[lane + 64];
    float4 b0 = ((const float4*)be)[lane], b1v = ((const float4*)be)[lane + 64];
    float ov[8];
    ov[0] = (v0.x - mu) * rs * g0.x + b0.x;
    ov[1] = (v0.y - mu) * rs * g0.y + b0.y;
    ov[2] = (v0.z - mu) * rs * g0.z + b0.z;
    ov[3] = (v0.w - mu) * rs * g0.w + b0.w;
    ov[4] = (v1.x - mu) * rs * g1v.x + b1v.x;
    ov[5] = (v1.y - mu) * rs * g1v.y + b1v.y;
    ov[6] = (v1.z - mu) * rs * g1v.z + b1v.z;
    ov[7] = (v1.w - mu) * rs * g1v.w + b1v.w;
    u16x4 h0, l0, h1, l1;
#pragma unroll
    for (int j = 0; j < 4; ++j) {
        unsigned short hb = f2bf(ov[j]);
        h0[j] = hb; l0[j] = f2bf(ov[j] - bf2f(hb));
        unsigned short hb2 = f2bf(ov[4 + j]);
        h1[j] = hb2; l1[j] = f2bf(ov[4 + j] - bf2f(hb2));
    }
    ((u16x4*)(Yh + (size_t)row * D_))[lane] = h0;
    ((u16x4*)(Yh + (size_t)row * D_))[lane + 64] = h1;
    ((u16x4*)(Yl + (size_t)row * D_))[lane] = l0;
    ((u16x4*)(Yl + (size_t)row * D_))[lane + 64] = l1;
}

// =================================================================
// LN2: y = LayerNorm((xh+xl) + r) fp32 out
// =================================================================
__global__ __launch_bounds__(256)
void add_ln_out(const unsigned short* __restrict__ Xh, const unsigned short* __restrict__ Xl,
                const float* __restrict__ R, const float* __restrict__ g,
                const float* __restrict__ be, float* __restrict__ Y) {
    const int row = blockIdx.x * 4 + (threadIdx.x >> 6);
    const int lane = threadIdx.x & 63;
    u16x4 xh0 = ((const u16x4*)(Xh + (size_t)row * D_))[lane];
    u16x4 xh1 = ((const u16x4*)(Xh + (size_t)row * D_))[lane + 64];
    u16x4 xl0 = ((const u16x4*)(Xl + (size_t)row * D_))[lane];
    u16x4 xl1 = ((const u16x4*)(Xl + (size_t)row * D_))[lane + 64];
    const float4* rp = (const float4*)(R + (size_t)row * D_);
    float4 r0 = rp[lane], r1 = rp[lane + 64];
    float v[8];
    v[0] = bf2f(xh0.x) + bf2f(xl0.x) + r0.x;
    v[1] = bf2f(xh0.y) + bf2f(xl0.y) + r0.y;
    v[2] = bf2f(xh0.z) + bf2f(xl0.z) + r0.z;
    v[3] = bf2f(xh0.w) + bf2f(xl0.w) + r0.w;
    v[4] = bf2f(xh1.x) + bf2f(xl1.x) + r1.x;
    v[5] = bf2f(xh1.y) + bf2f(xl1.y) + r1.y;
    v[6] = bf2f(xh1.z) + bf2f(xl1.z) + r1.z;
    v[7] = bf2f(xh1.w) + bf2f(xl1.w) + r1.w;
    float sum = 0.f;
#pragma unroll
    for (int j = 0; j < 8; ++j) sum += v[j];
    for (int d = 1; d < 64; d <<= 1) sum += __shfl_xor(sum, d);
    const float mu = sum * (1.0f / D_);
    float s2 = 0.f;
#pragma unroll
    for (int j = 0; j < 8; ++j) s2 += (v[j] - mu) * (v[j] - mu);
    for (int d = 1; d < 64; d <<= 1) s2 += __shfl_xor(s2, d);
    const float rs = rsqrtf(s2 * (1.0f / D_) + EPS_);
    float4 g0 = ((const float4*)g)[lane], g1v = ((const float4*)g)[lane + 64];
    float4 b0 = ((const float4*)be)[lane], b1v = ((const float4*)be)[lane + 64];
    float4 o0, o1;
    o0.x = (v[0] - mu) * rs * g0.x + b0.x;
    o0.y = (v[1] - mu) * rs * g0.y + b0.y;
    o0.z = (v[2] - mu) * rs * g0.z + b0.z;
    o0.w = (v[3] - mu) * rs * g0.w + b0.w;
    o1.x = (v[4] - mu) * rs * g1v.x + b1v.x;
    o1.y = (v[5] - mu) * rs * g1v.y + b1v.y;
    o1.z = (v[6] - mu) * rs * g1v.z + b1v.z;
    o1.w = (v[7] - mu) * rs * g1v.w + b1v.w;
    ((float4*)(Y + (size_t)row * D_))[lane] = o0;
    ((float4*)(Y + (size_t)row * D_))[lane + 64] = o1;
}

// =================================================================
extern "C" void kernel_launch(void* const* d_in, const int* in_sizes, int n_in,
                              void* d_out, int out_size, void* d_ws, size_t ws_size,
                              hipStream_t stream) {
    const float* x   = (const float*)d_in[0];
    const float* wq  = (const float*)d_in[1];
    const float* bq  = (const float*)d_in[2];
    const float* wk  = (const float*)d_in[3];
    const float* bk  = (const float*)d_in[4];
    const float* wv  = (const float*)d_in[5];
    const float* bv  = (const float*)d_in[6];
    const float* wo  = (const float*)d_in[7];
    const float* bo  = (const float*)d_in[8];
    const float* w1  = (const float*)d_in[9];
    const float* b1  = (const float*)d_in[10];
    const float* w2  = (const float*)d_in[11];
    const float* b2  = (const float*)d_in[12];
    const float* g1  = (const float*)d_in[13];
    const float* be1 = (const float*)d_in[14];
    const float* g2  = (const float*)d_in[15];
    const float* be2 = (const float*)d_in[16];

    char* W = (char*)d_ws;
#define WSOFF(kb) ((char*)W + (size_t)(kb) * 1024)
    unsigned short* wqh = (unsigned short*)WSOFF(0);
    unsigned short* wql = (unsigned short*)WSOFF(512);
    unsigned short* wkh = (unsigned short*)WSOFF(1024);
    unsigned short* wkl = (unsigned short*)WSOFF(1536);
    unsigned short* wvh = (unsigned short*)WSOFF(2048);
    unsigned short* wvl = (unsigned short*)WSOFF(2560);
    unsigned short* woh = (unsigned short*)WSOFF(3072);
    unsigned short* wol = (unsigned short*)WSOFF(3584);
    unsigned short* w1h = (unsigned short*)WSOFF(4096);
    unsigned short* w1l = (unsigned short*)WSOFF(5120);
    unsigned short* w2h = (unsigned short*)WSOFF(6144);
    unsigned short* w2l = (unsigned short*)WSOFF(7168);
    unsigned short* xh  = (unsigned short*)WSOFF(8192);
    unsigned short* xl  = (unsigned short*)WSOFF(16384);
    unsigned short* avh = (unsigned short*)WSOFF(8192);    // reuse xh
    unsigned short* avl = (unsigned short*)WSOFF(16384);   // reuse xl
    unsigned short* qh  = (unsigned short*)WSOFF(24576);
    unsigned short* ql  = (unsigned short*)WSOFF(32768);
    unsigned short* kh  = (unsigned short*)WSOFF(40960);
    unsigned short* kl  = (unsigned short*)WSOFF(49152);
    unsigned short* vh  = (unsigned short*)WSOFF(57344);
    float*          ao  = (float*)WSOFF(24576);            // reuse qh/ql
    unsigned short* x1h = (unsigned short*)WSOFF(40960);   // reuse kh
    unsigned short* x1l = (unsigned short*)WSOFF(49152);   // reuse kl
    unsigned short* hh  = (unsigned short*)WSOFF(8192);    // reuse avh/avl
    float*          ff  = (float*)WSOFF(24576);            // reuse ao

    const int M = B_ * S_;  // 8192
    dim3 blk(256);

    // splits
    split_f32<<<dim3(4096), blk, 0, stream>>>((const float4*)x, (u16x4*)xh, (u16x4*)xl, 1048576);
    split_f32<<<dim3(256), blk, 0, stream>>>((const float4*)wq, (u16x4*)wqh, (u16x4*)wql, 65536);
    split_f32<<<dim3(256), blk, 0, stream>>>((const float4*)wk, (u16x4*)wkh, (u16x4*)wkl, 65536);
    split_f32<<<dim3(256), blk, 0, stream>>>((const float4*)wv, (u16x4*)wvh, (u16x4*)wvl, 65536);
    split_f32<<<dim3(256), blk, 0, stream>>>((const float4*)wo, (u16x4*)woh, (u16x4*)wol, 65536);
    split_f32<<<dim3(512), blk, 0, stream>>>((const float4*)w1, (u16x4*)w1h, (u16x4*)w1l, 131072);
    split_f32<<<dim3(512), blk, 0, stream>>>((const float4*)w2, (u16x4*)w2h, (u16x4*)w2l, 131072);

    // QKV projections (split scatter for q,k; single-bf16 scatter for v)
    gemm_x3<2, true><<<dim3(64, 4), blk, 0, stream>>>(xh, xl, wqh, wql, bq, nullptr, qh, ql, M, D_, D_);
    gemm_x3<2, true><<<dim3(64, 4), blk, 0, stream>>>(xh, xl, wkh, wkl, bk, nullptr, kh, kl, M, D_, D_);
    gemm_x3<3, true><<<dim3(64, 4), blk, 0, stream>>>(xh, xl, wvh, wvl, bv, nullptr, vh, nullptr, M, D_, D_);
    // attention
    attn_fwd<<<dim3(S_ / 64, B_ * H_), blk, 0, stream>>>(qh, ql, kh, kl, vh, avh, avl);
    // output projection -> ao fp32
    gemm_x3<0, true><<<dim3(64, 4), blk, 0, stream>>>(avh, avl, woh, wol, bo, ao, nullptr, nullptr, M, D_, D_);
    // residual + LN1 -> split x1
    add_ln_split<<<dim3(M / 4), blk, 0, stream>>>(x, ao, g1, be1, x1h, x1l);
    // FFN1: relu -> single bf16 hh
    gemm_x3<1, true><<<dim3(64, 8), blk, 0, stream>>>(x1h, x1l, w1h, w1l, b1, nullptr, hh, nullptr, M, DFF_, D_);
    // FFN2: A single bf16 (2-MFMA path) -> ff fp32
    gemm_x3<0, false><<<dim3(64, 4), blk, 0, stream>>>(hh, nullptr, w2h, w2l, b2, ff, nullptr, nullptr, M, D_, DFF_);
    // residual + LN2 -> out
    add_ln_out<<<dim3(M / 4), blk, 0, stream>>>(x1h, x1l, ff, g2, be2, (float*)d_out);
}

// Round 8
// 419.108 us; speedup vs baseline: 2.7879x; 2.0848x over previous
//
#include <hip/hip_runtime.h>
#include <math.h>

#define B_ 4
#define S_ 2048
#define D_ 512
#define H_ 8
#define HD_ 64
#define DFF_ 1024
#define EPS_ 1e-5f

typedef _Float16 h16;
typedef __attribute__((ext_vector_type(4))) unsigned short u16x4;
typedef __attribute__((ext_vector_type(8))) unsigned short u16x8;
typedef __attribute__((ext_vector_type(8))) short s16x8;
typedef __attribute__((ext_vector_type(4))) float f32x4;

__device__ __forceinline__ unsigned short f2bf(float f) {
    union { float f; unsigned u; } a; a.f = f;
    unsigned r = a.u + 0x7fffu + ((a.u >> 16) & 1u);   // RNE
    return (unsigned short)(r >> 16);
}
__device__ __forceinline__ float bf2f(unsigned short u) {
    union { unsigned u; float f; } a; a.u = ((unsigned)u) << 16;
    return a.f;
}
__device__ __forceinline__ unsigned short f2h(float f) {
    h16 h = (h16)f;
    union { h16 h; unsigned short u; } a; a.h = h;
    return a.u;
}
__device__ __forceinline__ void mfma_bf16(f32x4& d, s16x8 a, s16x8 b) {
    asm("v_mfma_f32_16x16x32_bf16 %0, %1, %2, %0" : "+v"(d) : "v"(a), "v"(b));
}
__device__ __forceinline__ void mfma_f16(f32x4& d, s16x8 a, s16x8 b) {
    asm("v_mfma_f32_16x16x32_f16 %0, %1, %2, %0" : "+v"(d) : "v"(a), "v"(b));
}

#define GLOAD(gp, lp) __builtin_amdgcn_global_load_lds( \
    (const __attribute__((address_space(1))) unsigned int*)(gp), \
    (__attribute__((address_space(3))) unsigned int*)(lp), 16, 0, 0)

// =================================================================
// split fp32 -> (hi bf16, lo bf16)
// =================================================================
__global__ __launch_bounds__(256)
void split_f32(const float4* __restrict__ in, u16x4* __restrict__ oh,
               u16x4* __restrict__ ol, int n4) {
    int i = blockIdx.x * 256 + threadIdx.x;
    if (i >= n4) return;
    float4 v = in[i];
    u16x4 h, l;
    h.x = f2bf(v.x); l.x = f2bf(v.x - bf2f(h.x));
    h.y = f2bf(v.y); l.y = f2bf(v.y - bf2f(h.y));
    h.z = f2bf(v.z); l.z = f2bf(v.z - bf2f(h.z));
    h.w = f2bf(v.w); l.w = f2bf(v.w - bf2f(h.w));
    oh[i] = h; ol[i] = l;
}

// =================================================================
// bf16x3 MFMA GEMM: C = epi((Ah+Al) @ (Wh+Wl)^T + bias)
// EPI 0: Cf fp32 [M,N]. EPI 1: relu -> Ch bf16 [M,N].
// EPI 4: fp16 scatter [B,H,S,HD] scaled.
// =================================================================
template<int EPI, bool ASPLIT>
__global__ __launch_bounds__(256)
void gemm_x3(const unsigned short* __restrict__ Ah, const unsigned short* __restrict__ Al,
             const unsigned short* __restrict__ Wh, const unsigned short* __restrict__ Wl,
             const float* __restrict__ bias, float scale,
             float* __restrict__ Cf, unsigned short* __restrict__ Ch,
             int M, int N, int K) {
    __shared__ __align__(16) unsigned short AhL[4096];
    __shared__ __align__(16) unsigned short AlL[4096];
    __shared__ __align__(16) unsigned short WhL[4096];
    __shared__ __align__(16) unsigned short WlL[4096];
    const int tid = threadIdx.x;
    const int lane = tid & 63;
    const int wid = tid >> 6;
    const int wr = wid >> 1, wc = wid & 1;
    const int bm = blockIdx.x * 128, bn = blockIdx.y * 128;

    const int i0 = wid * 128 + lane, i1 = i0 + 64;
    const int r0 = i0 >> 2, r1 = i1 >> 2;
    const int s0 = (i0 & 3) ^ ((r0 >> 1) & 3);
    const int s1 = (i1 & 3) ^ ((r1 >> 1) & 3);
    const size_t a0 = (size_t)(bm + r0) * K + s0 * 8;
    const size_t a1 = (size_t)(bm + r1) * K + s1 * 8;
    const size_t w0 = (size_t)(bn + r0) * K + s0 * 8;
    const size_t w1 = (size_t)(bn + r1) * K + s1 * 8;
    const int lb0 = (wid * 2 + 0) * 512;
    const int lb1 = (wid * 2 + 1) * 512;

    f32x4 acc[4][4];
#pragma unroll
    for (int m = 0; m < 4; ++m)
#pragma unroll
        for (int n = 0; n < 4; ++n) acc[m][n] = f32x4{0.f, 0.f, 0.f, 0.f};

    const int fr = lane & 15, ks = lane >> 4;
    int offA[4], offW[4];
#pragma unroll
    for (int m = 0; m < 4; ++m) {
        int r = wr * 64 + m * 16 + fr;
        offA[m] = r * 32 + ((ks ^ ((r >> 1) & 3)) * 8);
    }
#pragma unroll
    for (int n = 0; n < 4; ++n) {
        int r = wc * 64 + n * 16 + fr;
        offW[n] = r * 32 + ((ks ^ ((r >> 1) & 3)) * 8);
    }

    for (int k0 = 0; k0 < K; k0 += 32) {
        __syncthreads();
        GLOAD(Ah + a0 + k0, AhL + lb0);
        GLOAD(Ah + a1 + k0, AhL + lb1);
        if (ASPLIT) {
            GLOAD(Al + a0 + k0, AlL + lb0);
            GLOAD(Al + a1 + k0, AlL + lb1);
        }
        GLOAD(Wh + w0 + k0, WhL + lb0);
        GLOAD(Wh + w1 + k0, WhL + lb1);
        GLOAD(Wl + w0 + k0, WlL + lb0);
        GLOAD(Wl + w1 + k0, WlL + lb1);
        __syncthreads();
        s16x8 fah[4], fal[4], fwh[4], fwl[4];
#pragma unroll
        for (int m = 0; m < 4; ++m) {
            fah[m] = *(const s16x8*)&AhL[offA[m]];
            if (ASPLIT) fal[m] = *(const s16x8*)&AlL[offA[m]];
        }
#pragma unroll
        for (int n = 0; n < 4; ++n) {
            fwh[n] = *(const s16x8*)&WhL[offW[n]];
            fwl[n] = *(const s16x8*)&WlL[offW[n]];
        }
#pragma unroll
        for (int m = 0; m < 4; ++m)
#pragma unroll
            for (int n = 0; n < 4; ++n) {
                mfma_bf16(acc[m][n], fah[m], fwh[n]);
                mfma_bf16(acc[m][n], fah[m], fwl[n]);
                if (ASPLIT) mfma_bf16(acc[m][n], fal[m], fwh[n]);
            }
    }

#pragma unroll
    for (int n = 0; n < 4; ++n) {
        int gc = bn + wc * 64 + n * 16 + fr;
        float bz = bias[gc];
#pragma unroll
        for (int m = 0; m < 4; ++m) {
            int grb = bm + wr * 64 + m * 16 + ks * 4;
#pragma unroll
            for (int j = 0; j < 4; ++j) {
                int gr = grb + j;
                float val = acc[m][n][j] + bz;
                if (EPI == 0) {
                    Cf[(size_t)gr * N + gc] = val;
                } else if (EPI == 1) {
                    Ch[(size_t)gr * N + gc] = f2bf(fmaxf(val, 0.f));
                } else {  // EPI 4: fp16 scatter [B,H,S,HD], scaled
                    int bb = gr >> 11, ss = gr & (S_ - 1);
                    int he = gc >> 6, hd = gc & 63;
                    Ch[((size_t)(bb * H_ + he) * S_ + ss) * HD_ + hd] = f2h(val * scale);
                }
            }
        }
    }
}

// =================================================================
// MFMA flash attention, BISECTION BUILD (round 7):
//  - no global_load_lds, no XOR swizzle, no EPI5 transposed V
//  - reg-staged vector loads -> padded LDS rows ([64][72] ushort,
//    16B-aligned fragment reads, worst 2-way bank alias = free)
//  - V transposed into LDS via scalar writes from [B,H,S,HD]
// Q [B*H][S][64] (pre-scaled 1/8), K,V [B*H][S][64] -> AV split bf16.
// 4 waves/block; wave = 16 q x 64 k tile; online softmax.
// =================================================================
__global__ __launch_bounds__(256)
void attn_mfma(const h16* __restrict__ Qg, const h16* __restrict__ Kg,
               const h16* __restrict__ Vg,
               unsigned short* __restrict__ AVh, unsigned short* __restrict__ AVl) {
    __shared__ __align__(16) unsigned short Ks[64 * 72];      // [key][hd], pad 8
    __shared__ __align__(16) unsigned short Vs[64 * 72];      // [hd][key], pad 8
    __shared__ __align__(16) unsigned short Ps[4 * 16 * 72];  // per-wave [q][key]
    const int tid = threadIdx.x, lane = tid & 63, w = tid >> 6;
    const int qb = blockIdx.x, bh = blockIdx.y;
    const int b = bh >> 3, h = bh & 7;
    const int lr = lane & 15, lk = lane >> 4;
    const size_t base = (size_t)bh * S_ * HD_;

    // Q fragments straight to registers (A: row=q=lane&15, 8 elems/kk)
    s16x8 qf[2];
    {
        const h16* qp = Qg + base + (size_t)(qb * 64 + w * 16 + lr) * HD_ + lk * 8;
        qf[0] = *(const s16x8*)(qp);
        qf[1] = *(const s16x8*)(qp + 32);
    }

    const int srow = tid >> 2;        // 0..63: key row staged by this thread
    const int sc = (tid & 3) * 16;    // hd chunk 0/16/32/48

    float m_[4], l_[4];
    f32x4 acc_o[4];
#pragma unroll
    for (int j = 0; j < 4; ++j) { m_[j] = -INFINITY; l_[j] = 0.f; }
#pragma unroll
    for (int n = 0; n < 4; ++n) acc_o[n] = f32x4{0.f, 0.f, 0.f, 0.f};

    for (int kt = 0; kt < S_ / 64; ++kt) {
        // global loads issued before the barrier (no LDS dependency)
        const unsigned short* kp = (const unsigned short*)(Kg + base) +
                                   (size_t)(kt * 64 + srow) * HD_ + sc;
        const unsigned short* vp = (const unsigned short*)(Vg + base) +
                                   (size_t)(kt * 64 + srow) * HD_ + sc;
        u16x8 ka = *(const u16x8*)kp, kb = *(const u16x8*)(kp + 8);
        u16x8 va = *(const u16x8*)vp, vb = *(const u16x8*)(vp + 8);
        __syncthreads();   // previous tile fully consumed
        *(u16x8*)&Ks[srow * 72 + sc] = ka;
        *(u16x8*)&Ks[srow * 72 + sc + 8] = kb;
#pragma unroll
        for (int e = 0; e < 8; ++e) {
            Vs[(sc + e) * 72 + srow] = va[e];          // Vs[hd][key]
            Vs[(sc + 8 + e) * 72 + srow] = vb[e];
        }
        __syncthreads();   // staging visible

        // ---- scores: acc_s[n] = Q(16x64) @ K^T ----
        f32x4 acc_s[4];
#pragma unroll
        for (int n = 0; n < 4; ++n) acc_s[n] = f32x4{0.f, 0.f, 0.f, 0.f};
#pragma unroll
        for (int n = 0; n < 4; ++n) {
            int krow = n * 16 + lr;                    // B: col=key=lane&15
#pragma unroll
            for (int kk = 0; kk < 2; ++kk) {
                s16x8 kf = *(const s16x8*)&Ks[krow * 72 + kk * 32 + lk * 8];
                mfma_f16(acc_s[n], qf[kk], kf);
            }
        }

        // ---- online softmax (D: row q=lk*4+j, col key=n*16+lr) ----
        unsigned short* pw = Ps + w * (16 * 72);
#pragma unroll
        for (int j = 0; j < 4; ++j) {
            float mloc = fmaxf(fmaxf(acc_s[0][j], acc_s[1][j]),
                               fmaxf(acc_s[2][j], acc_s[3][j]));
            for (int d = 1; d < 16; d <<= 1) mloc = fmaxf(mloc, __shfl_xor(mloc, d));
            float mc = fmaxf(m_[j], mloc);
            float al = (m_[j] == -INFINITY) ? 0.f : __expf(m_[j] - mc);
            int q = lk * 4 + j;
            float ps = 0.f;
#pragma unroll
            for (int n = 0; n < 4; ++n) {
                float p = __expf(acc_s[n][j] - mc);
                ps += p;
                pw[q * 72 + n * 16 + lr] = f2h(p);     // P[q][key], plain
            }
            for (int d = 1; d < 16; d <<= 1) ps += __shfl_xor(ps, d);
            l_[j] = l_[j] * al + ps;
            m_[j] = mc;
#pragma unroll
            for (int n = 0; n < 4; ++n) acc_o[n][j] *= al;
        }

        __syncthreads();   // fence: P writes -> P fragment reads

        // ---- PV: acc_o[n2] += P(16x64) @ V ----
        s16x8 pf[2];
#pragma unroll
        for (int kk = 0; kk < 2; ++kk)
            pf[kk] = *(const s16x8*)&pw[lr * 72 + kk * 32 + lk * 8];
#pragma unroll
        for (int n2 = 0; n2 < 4; ++n2) {
            int vrow = n2 * 16 + lr;                   // B: col=hd=lane&15
#pragma unroll
            for (int kk = 0; kk < 2; ++kk) {
                s16x8 vf = *(const s16x8*)&Vs[vrow * 72 + kk * 32 + lk * 8];
                mfma_f16(acc_o[n2], pf[kk], vf);
            }
        }
    }

    // epilogue: /l, split-bf16 write AV[b][s][h*64+hd]
#pragma unroll
    for (int j = 0; j < 4; ++j) {
        float inv = 1.0f / l_[j];
        int srw = qb * 64 + w * 16 + lk * 4 + j;
        size_t rb = ((size_t)b * S_ + srw) * D_ + h * HD_;
#pragma unroll
        for (int n2 = 0; n2 < 4; ++n2) {
            float val = acc_o[n2][j] * inv;
            unsigned short hb = f2bf(val);
            AVh[rb + n2 * 16 + lr] = hb;
            AVl[rb + n2 * 16 + lr] = f2bf(val - bf2f(hb));
        }
    }
}

// =================================================================
// LN1: y = LayerNorm(x + r) -> split bf16
// =================================================================
__global__ __launch_bounds__(256)
void add_ln_split(const float* __restrict__ X, const float* __restrict__ R,
                  const float* __restrict__ g, const float* __restrict__ be,
                  unsigned short* __restrict__ Yh, unsigned short* __restrict__ Yl) {
    const int row = blockIdx.x * 4 + (threadIdx.x >> 6);
    const int lane = threadIdx.x & 63;
    const float4* xp = (const float4*)(X + (size_t)row * D_);
    const float4* rp = (const float4*)(R + (size_t)row * D_);
    float4 v0 = xp[lane], v1 = xp[lane + 64];
    float4 r0 = rp[lane], r1 = rp[lane + 64];
    v0.x += r0.x; v0.y += r0.y; v0.z += r0.z; v0.w += r0.w;
    v1.x += r1.x; v1.y += r1.y; v1.z += r1.z; v1.w += r1.w;
    float sum = v0.x + v0.y + v0.z + v0.w + v1.x + v1.y + v1.z + v1.w;
    for (int d = 1; d < 64; d <<= 1) sum += __shfl_xor(sum, d);
    const float mu = sum * (1.0f / D_);
    float s2 = (v0.x - mu) * (v0.x - mu) + (v0.y - mu) * (v0.y - mu) +
               (v0.z - mu) * (v0.z - mu) + (v0.w - mu) * (v0.w - mu) +
               (v1.x - mu) * (v1.x - mu) + (v1.y - mu) * (v1.y - mu) +
               (v1.z - mu) * (v1.z - mu) + (v1.w - mu) * (v1.w - mu);
    for (int d = 1; d < 64; d <<= 1) s2 += __shfl_xor(s2, d);
    const float rs = rsqrtf(s2 * (1.0f / D_) + EPS_);
    float4 g0 = ((const float4*)g)[lane], g1v = ((const float4*)g)[lane + 64];
    float4 b0 = ((const float4*)be)[lane], b1v = ((const float4*)be)[lane + 64];
    float ov[8];
    ov[0] = (v0.x - mu) * rs * g0.x + b0.x;
    ov[1] = (v0.y - mu) * rs * g0.y + b0.y;
    ov[2] = (v0.z - mu) * rs * g0.z + b0.z;
    ov[3] = (v0.w - mu) * rs * g0.w + b0.w;
    ov[4] = (v1.x - mu) * rs * g1v.x + b1v.x;
    ov[5] = (v1.y - mu) * rs * g1v.y + b1v.y;
    ov[6] = (v1.z - mu) * rs * g1v.z + b1v.z;
    ov[7] = (v1.w - mu) * rs * g1v.w + b1v.w;
    u16x4 h0, l0, h1, l1;
#pragma unroll
    for (int j = 0; j < 4; ++j) {
        unsigned short hb = f2bf(ov[j]);
        h0[j] = hb; l0[j] = f2bf(ov[j] - bf2f(hb));
        unsigned short hb2 = f2bf(ov[4 + j]);
        h1[j] = hb2; l1[j] = f2bf(ov[4 + j] - bf2f(hb2));
    }
    ((u16x4*)(Yh + (size_t)row * D_))[lane] = h0;
    ((u16x4*)(Yh + (size_t)row * D_))[lane + 64] = h1;
    ((u16x4*)(Yl + (size_t)row * D_))[lane] = l0;
    ((u16x4*)(Yl + (size_t)row * D_))[lane + 64] = l1;
}

// =================================================================
// LN2: y = LayerNorm((xh+xl) + r) fp32 out
// =================================================================
__global__ __launch_bounds__(256)
void add_ln_out(const unsigned short* __restrict__ Xh, const unsigned short* __restrict__ Xl,
                const float* __restrict__ R, const float* __restrict__ g,
                const float* __restrict__ be, float* __restrict__ Y) {
    const int row = blockIdx.x * 4 + (threadIdx.x >> 6);
    const int lane = threadIdx.x & 63;
    u16x4 xh0 = ((const u16x4*)(Xh + (size_t)row * D_))[lane];
    u16x4 xh1 = ((const u16x4*)(Xh + (size_t)row * D_))[lane + 64];
    u16x4 xl0 = ((const u16x4*)(Xl + (size_t)row * D_))[lane];
    u16x4 xl1 = ((const u16x4*)(Xl + (size_t)row * D_))[lane + 64];
    const float4* rp = (const float4*)(R + (size_t)row * D_);
    float4 r0 = rp[lane], r1 = rp[lane + 64];
    float v[8];
    v[0] = bf2f(xh0.x) + bf2f(xl0.x) + r0.x;
    v[1] = bf2f(xh0.y) + bf2f(xl0.y) + r0.y;
    v[2] = bf2f(xh0.z) + bf2f(xl0.z) + r0.z;
    v[3] = bf2f(xh0.w) + bf2f(xl0.w) + r0.w;
    v[4] = bf2f(xh1.x) + bf2f(xl1.x) + r1.x;
    v[5] = bf2f(xh1.y) + bf2f(xl1.y) + r1.y;
    v[6] = bf2f(xh1.z) + bf2f(xl1.z) + r1.z;
    v[7] = bf2f(xh1.w) + bf2f(xl1.w) + r1.w;
    float sum = 0.f;
#pragma unroll
    for (int j = 0; j < 8; ++j) sum += v[j];
    for (int d = 1; d < 64; d <<= 1) sum += __shfl_xor(sum, d);
    const float mu = sum * (1.0f / D_);
    float s2 = 0.f;
#pragma unroll
    for (int j = 0; j < 8; ++j) s2 += (v[j] - mu) * (v[j] - mu);
    for (int d = 1; d < 64; d <<= 1) s2 += __shfl_xor(s2, d);
    const float rs = rsqrtf(s2 * (1.0f / D_) + EPS_);
    float4 g0 = ((const float4*)g)[lane], g1v = ((const float4*)g)[lane + 64];
    float4 b0 = ((const float4*)be)[lane], b1v = ((const float4*)be)[lane + 64];
    float4 o0, o1;
    o0.x = (v[0] - mu) * rs * g0.x + b0.x;
    o0.y = (v[1] - mu) * rs * g0.y + b0.y;
    o0.z = (v[2] - mu) * rs * g0.z + b0.z;
    o0.w = (v[3] - mu) * rs * g0.w + b0.w;
    o1.x = (v[4] - mu) * rs * g1v.x + b1v.x;
    o1.y = (v[5] - mu) * rs * g1v.y + b1v.y;
    o1.z = (v[6] - mu) * rs * g1v.z + b1v.z;
    o1.w = (v[7] - mu) * rs * g1v.w + b1v.w;
    ((float4*)(Y + (size_t)row * D_))[lane] = o0;
    ((float4*)(Y + (size_t)row * D_))[lane + 64] = o1;
}

// =================================================================
extern "C" void kernel_launch(void* const* d_in, const int* in_sizes, int n_in,
                              void* d_out, int out_size, void* d_ws, size_t ws_size,
                              hipStream_t stream) {
    const float* x   = (const float*)d_in[0];
    const float* wq  = (const float*)d_in[1];
    const float* bq  = (const float*)d_in[2];
    const float* wk  = (const float*)d_in[3];
    const float* bk  = (const float*)d_in[4];
    const float* wv  = (const float*)d_in[5];
    const float* bv  = (const float*)d_in[6];
    const float* wo  = (const float*)d_in[7];
    const float* bo  = (const float*)d_in[8];
    const float* w1  = (const float*)d_in[9];
    const float* b1  = (const float*)d_in[10];
    const float* w2  = (const float*)d_in[11];
    const float* b2  = (const float*)d_in[12];
    const float* g1  = (const float*)d_in[13];
    const float* be1 = (const float*)d_in[14];
    const float* g2  = (const float*)d_in[15];
    const float* be2 = (const float*)d_in[16];

    char* W = (char*)d_ws;
#define WSOFF(kb) ((char*)W + (size_t)(kb) * 1024)
    unsigned short* wqh = (unsigned short*)WSOFF(0);
    unsigned short* wql = (unsigned short*)WSOFF(512);
    unsigned short* wkh = (unsigned short*)WSOFF(1024);
    unsigned short* wkl = (unsigned short*)WSOFF(1536);
    unsigned short* wvh = (unsigned short*)WSOFF(2048);
    unsigned short* wvl = (unsigned short*)WSOFF(2560);
    unsigned short* woh = (unsigned short*)WSOFF(3072);
    unsigned short* wol = (unsigned short*)WSOFF(3584);
    unsigned short* w1h = (unsigned short*)WSOFF(4096);
    unsigned short* w1l = (unsigned short*)WSOFF(5120);
    unsigned short* w2h = (unsigned short*)WSOFF(6144);
    unsigned short* w2l = (unsigned short*)WSOFF(7168);
    unsigned short* xh  = (unsigned short*)WSOFF(8192);
    unsigned short* xl  = (unsigned short*)WSOFF(16384);
    unsigned short* qf  = (unsigned short*)WSOFF(24576);   // fp16 [B,H,S,64]
    unsigned short* kf  = (unsigned short*)WSOFF(32768);   // fp16 [B,H,S,64]
    unsigned short* vf  = (unsigned short*)WSOFF(40960);   // fp16 [B,H,S,64]
    unsigned short* avh = (unsigned short*)WSOFF(8192);    // reuse xh
    unsigned short* avl = (unsigned short*)WSOFF(16384);   // reuse xl
    float*          ao  = (float*)WSOFF(24576);            // reuse qf,kf (16MB)
    unsigned short* x1h = (unsigned short*)WSOFF(40960);   // reuse vf
    unsigned short* x1l = (unsigned short*)WSOFF(49152);
    unsigned short* hh  = (unsigned short*)WSOFF(8192);    // reuse avh/avl
    float*          ff  = (float*)WSOFF(24576);            // reuse ao

    const int M = B_ * S_;  // 8192
    dim3 blk(256);

    split_f32<<<dim3(4096), blk, 0, stream>>>((const float4*)x, (u16x4*)xh, (u16x4*)xl, 1048576);
    split_f32<<<dim3(256), blk, 0, stream>>>((const float4*)wq, (u16x4*)wqh, (u16x4*)wql, 65536);
    split_f32<<<dim3(256), blk, 0, stream>>>((const float4*)wk, (u16x4*)wkh, (u16x4*)wkl, 65536);
    split_f32<<<dim3(256), blk, 0, stream>>>((const float4*)wv, (u16x4*)wvh, (u16x4*)wvl, 65536);
    split_f32<<<dim3(256), blk, 0, stream>>>((const float4*)wo, (u16x4*)woh, (u16x4*)wol, 65536);
    split_f32<<<dim3(512), blk, 0, stream>>>((const float4*)w1, (u16x4*)w1h, (u16x4*)w1l, 131072);
    split_f32<<<dim3(512), blk, 0, stream>>>((const float4*)w2, (u16x4*)w2h, (u16x4*)w2l, 131072);

    // QKV projections -> fp16 [B,H,S,HD] (Q pre-scaled by 1/8)
    gemm_x3<4, true><<<dim3(64, 4), blk, 0, stream>>>(xh, xl, wqh, wql, bq, 0.125f, nullptr, qf, M, D_, D_);
    gemm_x3<4, true><<<dim3(64, 4), blk, 0, stream>>>(xh, xl, wkh, wkl, bk, 1.0f, nullptr, kf, M, D_, D_);
    gemm_x3<4, true><<<dim3(64, 4), blk, 0, stream>>>(xh, xl, wvh, wvl, bv, 1.0f, nullptr, vf, M, D_, D_);
    // MFMA flash attention (plain-LDS bisection build)
    attn_mfma<<<dim3(S_ / 64, B_ * H_), blk, 0, stream>>>(
        (const h16*)qf, (const h16*)kf, (const h16*)vf, avh, avl);
    // output projection -> ao fp32
    gemm_x3<0, true><<<dim3(64, 4), blk, 0, stream>>>(avh, avl, woh, wol, bo, 1.0f, ao, nullptr, M, D_, D_);
    add_ln_split<<<dim3(M / 4), blk, 0, stream>>>(x, ao, g1, be1, x1h, x1l);
    gemm_x3<1, true><<<dim3(64, 8), blk, 0, stream>>>(x1h, x1l, w1h, w1l, b1, 1.0f, nullptr, hh, M, DFF_, D_);
    gemm_x3<0, false><<<dim3(64, 4), blk, 0, stream>>>(hh, nullptr, w2h, w2l, b2, 1.0f, ff, nullptr, M, D_, DFF_);
    add_ln_out<<<dim3(M / 4), blk, 0, stream>>>(x1h, x1l, ff, g2, be2, (float*)d_out);
}

// Round 9
// 375.740 us; speedup vs baseline: 3.1097x; 1.1154x over previous
//
#include <hip/hip_runtime.h>
#include <math.h>

#define B_ 4
#define S_ 2048
#define D_ 512
#define H_ 8
#define HD_ 64
#define DFF_ 1024
#define EPS_ 1e-5f

typedef _Float16 h16;
typedef __attribute__((ext_vector_type(4))) unsigned short u16x4;
typedef __attribute__((ext_vector_type(8))) unsigned short u16x8;
typedef __attribute__((ext_vector_type(8))) short s16x8;
typedef __attribute__((ext_vector_type(4))) float f32x4;

__device__ __forceinline__ unsigned short f2bf(float f) {
    union { float f; unsigned u; } a; a.f = f;
    unsigned r = a.u + 0x7fffu + ((a.u >> 16) & 1u);   // RNE
    return (unsigned short)(r >> 16);
}
__device__ __forceinline__ float bf2f(unsigned short u) {
    union { unsigned u; float f; } a; a.u = ((unsigned)u) << 16;
    return a.f;
}
__device__ __forceinline__ unsigned short f2h(float f) {
    h16 h = (h16)f;
    union { h16 h; unsigned short u; } a; a.h = h;
    return a.u;
}
__device__ __forceinline__ void mfma_bf16(f32x4& d, s16x8 a, s16x8 b) {
    asm("v_mfma_f32_16x16x32_bf16 %0, %1, %2, %0" : "+v"(d) : "v"(a), "v"(b));
}
__device__ __forceinline__ void mfma_f16(f32x4& d, s16x8 a, s16x8 b) {
    asm("v_mfma_f32_16x16x32_f16 %0, %1, %2, %0" : "+v"(d) : "v"(a), "v"(b));
}

#define GLOAD(gp, lp) __builtin_amdgcn_global_load_lds( \
    (const __attribute__((address_space(1))) unsigned int*)(gp), \
    (__attribute__((address_space(3))) unsigned int*)(lp), 16, 0, 0)

// =================================================================
// split fp32 -> (hi bf16, lo bf16)
// =================================================================
__global__ __launch_bounds__(256)
void split_f32(const float4* __restrict__ in, u16x4* __restrict__ oh,
               u16x4* __restrict__ ol, int n4) {
    int i = blockIdx.x * 256 + threadIdx.x;
    if (i >= n4) return;
    float4 v = in[i];
    u16x4 h, l;
    h.x = f2bf(v.x); l.x = f2bf(v.x - bf2f(h.x));
    h.y = f2bf(v.y); l.y = f2bf(v.y - bf2f(h.y));
    h.z = f2bf(v.z); l.z = f2bf(v.z - bf2f(h.z));
    h.w = f2bf(v.w); l.w = f2bf(v.w - bf2f(h.w));
    oh[i] = h; ol[i] = l;
}

// =================================================================
// bf16x3 MFMA GEMM: C = epi((Ah+Al) @ (Wh+Wl)^T + bias)
// EPI 0: Cf fp32 [M,N]. EPI 1: relu -> Ch bf16 [M,N].
// EPI 4: fp16 scatter [B,H,S,HD] scaled.
// EPI 6: fused QKV — N=1536; sel=gc>>9 routes to Ch/Ch2/Ch3 with
//        bias/bias2/bias3; q (sel 0) scaled by `scale`.
// =================================================================
template<int EPI, bool ASPLIT>
__global__ __launch_bounds__(256)
void gemm_x3(const unsigned short* __restrict__ Ah, const unsigned short* __restrict__ Al,
             const unsigned short* __restrict__ Wh, const unsigned short* __restrict__ Wl,
             const float* __restrict__ bias, const float* __restrict__ bias2,
             const float* __restrict__ bias3, float scale,
             float* __restrict__ Cf, unsigned short* __restrict__ Ch,
             unsigned short* __restrict__ Ch2, unsigned short* __restrict__ Ch3,
             int M, int N, int K) {
    __shared__ __align__(16) unsigned short AhL[4096];
    __shared__ __align__(16) unsigned short AlL[4096];
    __shared__ __align__(16) unsigned short WhL[4096];
    __shared__ __align__(16) unsigned short WlL[4096];
    const int tid = threadIdx.x;
    const int lane = tid & 63;
    const int wid = tid >> 6;
    const int wr = wid >> 1, wc = wid & 1;
    const int bm = blockIdx.x * 128, bn = blockIdx.y * 128;

    const int i0 = wid * 128 + lane, i1 = i0 + 64;
    const int r0 = i0 >> 2, r1 = i1 >> 2;
    const int s0 = (i0 & 3) ^ ((r0 >> 1) & 3);
    const int s1 = (i1 & 3) ^ ((r1 >> 1) & 3);
    const size_t a0 = (size_t)(bm + r0) * K + s0 * 8;
    const size_t a1 = (size_t)(bm + r1) * K + s1 * 8;
    const size_t w0 = (size_t)(bn + r0) * K + s0 * 8;
    const size_t w1 = (size_t)(bn + r1) * K + s1 * 8;
    const int lb0 = (wid * 2 + 0) * 512;
    const int lb1 = (wid * 2 + 1) * 512;

    f32x4 acc[4][4];
#pragma unroll
    for (int m = 0; m < 4; ++m)
#pragma unroll
        for (int n = 0; n < 4; ++n) acc[m][n] = f32x4{0.f, 0.f, 0.f, 0.f};

    const int fr = lane & 15, ks = lane >> 4;
    int offA[4], offW[4];
#pragma unroll
    for (int m = 0; m < 4; ++m) {
        int r = wr * 64 + m * 16 + fr;
        offA[m] = r * 32 + ((ks ^ ((r >> 1) & 3)) * 8);
    }
#pragma unroll
    for (int n = 0; n < 4; ++n) {
        int r = wc * 64 + n * 16 + fr;
        offW[n] = r * 32 + ((ks ^ ((r >> 1) & 3)) * 8);
    }

    for (int k0 = 0; k0 < K; k0 += 32) {
        __syncthreads();
        GLOAD(Ah + a0 + k0, AhL + lb0);
        GLOAD(Ah + a1 + k0, AhL + lb1);
        if (ASPLIT) {
            GLOAD(Al + a0 + k0, AlL + lb0);
            GLOAD(Al + a1 + k0, AlL + lb1);
        }
        GLOAD(Wh + w0 + k0, WhL + lb0);
        GLOAD(Wh + w1 + k0, WhL + lb1);
        GLOAD(Wl + w0 + k0, WlL + lb0);
        GLOAD(Wl + w1 + k0, WlL + lb1);
        __syncthreads();
        s16x8 fah[4], fal[4], fwh[4], fwl[4];
#pragma unroll
        for (int m = 0; m < 4; ++m) {
            fah[m] = *(const s16x8*)&AhL[offA[m]];
            if (ASPLIT) fal[m] = *(const s16x8*)&AlL[offA[m]];
        }
#pragma unroll
        for (int n = 0; n < 4; ++n) {
            fwh[n] = *(const s16x8*)&WhL[offW[n]];
            fwl[n] = *(const s16x8*)&WlL[offW[n]];
        }
#pragma unroll
        for (int m = 0; m < 4; ++m)
#pragma unroll
            for (int n = 0; n < 4; ++n) {
                mfma_bf16(acc[m][n], fah[m], fwh[n]);
                mfma_bf16(acc[m][n], fah[m], fwl[n]);
                if (ASPLIT) mfma_bf16(acc[m][n], fal[m], fwh[n]);
            }
    }

#pragma unroll
    for (int n = 0; n < 4; ++n) {
        int gc = bn + wc * 64 + n * 16 + fr;
        if (EPI == 6) {
            // fused QKV scatter: sel uniform per block (128 | 512 boundaries)
            int sel = gc >> 9, cc = gc & 511;
            int he = cc >> 6, hd = cc & 63;
            float bz = (sel == 0 ? bias : (sel == 1 ? bias2 : bias3))[cc];
            unsigned short* Co = (sel == 0 ? Ch : (sel == 1 ? Ch2 : Ch3));
            float scl = (sel == 0) ? scale : 1.0f;
#pragma unroll
            for (int m = 0; m < 4; ++m) {
                int grb = bm + wr * 64 + m * 16 + ks * 4;
#pragma unroll
                for (int j = 0; j < 4; ++j) {
                    int gr = grb + j;
                    int bb = gr >> 11, ss = gr & (S_ - 1);
                    Co[((size_t)(bb * H_ + he) * S_ + ss) * HD_ + hd] =
                        f2h((acc[m][n][j] + bz) * scl);
                }
            }
        } else {
            float bz = bias[gc];
#pragma unroll
            for (int m = 0; m < 4; ++m) {
                int grb = bm + wr * 64 + m * 16 + ks * 4;
#pragma unroll
                for (int j = 0; j < 4; ++j) {
                    int gr = grb + j;
                    float val = acc[m][n][j] + bz;
                    if (EPI == 0) {
                        Cf[(size_t)gr * N + gc] = val;
                    } else if (EPI == 1) {
                        Ch[(size_t)gr * N + gc] = f2bf(fmaxf(val, 0.f));
                    } else {  // EPI 4: fp16 scatter [B,H,S,HD], scaled
                        int bb = gr >> 11, ss = gr & (S_ - 1);
                        int he = gc >> 6, hd = gc & 63;
                        Ch[((size_t)(bb * H_ + he) * S_ + ss) * HD_ + hd] = f2h(val * scale);
                    }
                }
            }
        }
    }
}

// =================================================================
// MFMA flash attention (round 9 = round 8 + conflict-free V layout):
// V[key][hd] stored at Vs[hd*72 + ((key + (hd&48)) & 63)] — column
// shift by 16*(hd>>4) spreads the 4 hd-groups across banks on the
// scalar transpose writes (8-way -> ~2-way); reads stay 16B-aligned
// contiguous-8 (base (kk*32+lk*8+n2*16)&63, compile-time per n2).
// =================================================================
__global__ __launch_bounds__(256)
void attn_mfma(const h16* __restrict__ Qg, const h16* __restrict__ Kg,
               const h16* __restrict__ Vg,
               unsigned short* __restrict__ AVh, unsigned short* __restrict__ AVl) {
    __shared__ __align__(16) unsigned short Ks[64 * 72];      // [key][hd], pad 8
    __shared__ __align__(16) unsigned short Vs[64 * 72];      // [hd][key shifted]
    __shared__ __align__(16) unsigned short Ps[4 * 16 * 72];  // per-wave [q][key]
    const int tid = threadIdx.x, lane = tid & 63, w = tid >> 6;
    const int qb = blockIdx.x, bh = blockIdx.y;
    const int b = bh >> 3, h = bh & 7;
    const int lr = lane & 15, lk = lane >> 4;
    const size_t base = (size_t)bh * S_ * HD_;

    // Q fragments straight to registers (A: row=q=lane&15, 8 elems/kk)
    s16x8 qf[2];
    {
        const h16* qp = Qg + base + (size_t)(qb * 64 + w * 16 + lr) * HD_ + lk * 8;
        qf[0] = *(const s16x8*)(qp);
        qf[1] = *(const s16x8*)(qp + 32);
    }

    const int srow = tid >> 2;        // 0..63: key row staged by this thread
    const int sc = (tid & 3) * 16;    // hd chunk 0/16/32/48
    const int vcol = (srow + sc) & 63;  // shifted column for V writes

    float m_[4], l_[4];
    f32x4 acc_o[4];
#pragma unroll
    for (int j = 0; j < 4; ++j) { m_[j] = -INFINITY; l_[j] = 0.f; }
#pragma unroll
    for (int n = 0; n < 4; ++n) acc_o[n] = f32x4{0.f, 0.f, 0.f, 0.f};

    for (int kt = 0; kt < S_ / 64; ++kt) {
        // global loads issued before the barrier (no LDS dependency)
        const unsigned short* kp = (const unsigned short*)(Kg + base) +
                                   (size_t)(kt * 64 + srow) * HD_ + sc;
        const unsigned short* vp = (const unsigned short*)(Vg + base) +
                                   (size_t)(kt * 64 + srow) * HD_ + sc;
        u16x8 ka = *(const u16x8*)kp, kb = *(const u16x8*)(kp + 8);
        u16x8 va = *(const u16x8*)vp, vb = *(const u16x8*)(vp + 8);
        __syncthreads();   // previous tile fully consumed
        *(u16x8*)&Ks[srow * 72 + sc] = ka;
        *(u16x8*)&Ks[srow * 72 + sc + 8] = kb;
#pragma unroll
        for (int e = 0; e < 8; ++e) {
            Vs[(sc + e) * 72 + vcol]     = va[e];   // Vs[hd][key+hd&48 mod 64]
            Vs[(sc + 8 + e) * 72 + vcol] = vb[e];
        }
        __syncthreads();   // staging visible

        // ---- scores: acc_s[n] = Q(16x64) @ K^T ----
        f32x4 acc_s[4];
#pragma unroll
        for (int n = 0; n < 4; ++n) acc_s[n] = f32x4{0.f, 0.f, 0.f, 0.f};
#pragma unroll
        for (int n = 0; n < 4; ++n) {
            int krow = n * 16 + lr;                    // B: col=key=lane&15
#pragma unroll
            for (int kk = 0; kk < 2; ++kk) {
                s16x8 kf = *(const s16x8*)&Ks[krow * 72 + kk * 32 + lk * 8];
                mfma_f16(acc_s[n], qf[kk], kf);
            }
        }

        // ---- online softmax (D: row q=lk*4+j, col key=n*16+lr) ----
        unsigned short* pw = Ps + w * (16 * 72);
#pragma unroll
        for (int j = 0; j < 4; ++j) {
            float mloc = fmaxf(fmaxf(acc_s[0][j], acc_s[1][j]),
                               fmaxf(acc_s[2][j], acc_s[3][j]));
            for (int d = 1; d < 16; d <<= 1) mloc = fmaxf(mloc, __shfl_xor(mloc, d));
            float mc = fmaxf(m_[j], mloc);
            float al = (m_[j] == -INFINITY) ? 0.f : __expf(m_[j] - mc);
            int q = lk * 4 + j;
            float ps = 0.f;
#pragma unroll
            for (int n = 0; n < 4; ++n) {
                float p = __expf(acc_s[n][j] - mc);
                ps += p;
                pw[q * 72 + n * 16 + lr] = f2h(p);     // P[q][key], plain
            }
            for (int d = 1; d < 16; d <<= 1) ps += __shfl_xor(ps, d);
            l_[j] = l_[j] * al + ps;
            m_[j] = mc;
#pragma unroll
            for (int n = 0; n < 4; ++n) acc_o[n][j] *= al;
        }

        __syncthreads();   // fence: P writes -> P fragment reads

        // ---- PV: acc_o[n2] += P(16x64) @ V ----
        s16x8 pf[2];
#pragma unroll
        for (int kk = 0; kk < 2; ++kk)
            pf[kk] = *(const s16x8*)&pw[lr * 72 + kk * 32 + lk * 8];
#pragma unroll
        for (int n2 = 0; n2 < 4; ++n2) {
            int vrow = n2 * 16 + lr;                   // B: col=hd=lane&15
#pragma unroll
            for (int kk = 0; kk < 2; ++kk) {
                int cb = (kk * 32 + lk * 8 + n2 * 16) & 63;   // shifted key base
                s16x8 vf = *(const s16x8*)&Vs[vrow * 72 + cb];
                mfma_f16(acc_o[n2], pf[kk], vf);
            }
        }
    }

    // epilogue: /l, split-bf16 write AV[b][s][h*64+hd]
#pragma unroll
    for (int j = 0; j < 4; ++j) {
        float inv = 1.0f / l_[j];
        int srw = qb * 64 + w * 16 + lk * 4 + j;
        size_t rb = ((size_t)b * S_ + srw) * D_ + h * HD_;
#pragma unroll
        for (int n2 = 0; n2 < 4; ++n2) {
            float val = acc_o[n2][j] * inv;
            unsigned short hb = f2bf(val);
            AVh[rb + n2 * 16 + lr] = hb;
            AVl[rb + n2 * 16 + lr] = f2bf(val - bf2f(hb));
        }
    }
}

// =================================================================
// LN1: y = LayerNorm(x + r) -> split bf16
// =================================================================
__global__ __launch_bounds__(256)
void add_ln_split(const float* __restrict__ X, const float* __restrict__ R,
                  const float* __restrict__ g, const float* __restrict__ be,
                  unsigned short* __restrict__ Yh, unsigned short* __restrict__ Yl) {
    const int row = blockIdx.x * 4 + (threadIdx.x >> 6);
    const int lane = threadIdx.x & 63;
    const float4* xp = (const float4*)(X + (size_t)row * D_);
    const float4* rp = (const float4*)(R + (size_t)row * D_);
    float4 v0 = xp[lane], v1 = xp[lane + 64];
    float4 r0 = rp[lane], r1 = rp[lane + 64];
    v0.x += r0.x; v0.y += r0.y; v0.z += r0.z; v0.w += r0.w;
    v1.x += r1.x; v1.y += r1.y; v1.z += r1.z; v1.w += r1.w;
    float sum = v0.x + v0.y + v0.z + v0.w + v1.x + v1.y + v1.z + v1.w;
    for (int d = 1; d < 64; d <<= 1) sum += __shfl_xor(sum, d);
    const float mu = sum * (1.0f / D_);
    float s2 = (v0.x - mu) * (v0.x - mu) + (v0.y - mu) * (v0.y - mu) +
               (v0.z - mu) * (v0.z - mu) + (v0.w - mu) * (v0.w - mu) +
               (v1.x - mu) * (v1.x - mu) + (v1.y - mu) * (v1.y - mu) +
               (v1.z - mu) * (v1.z - mu) + (v1.w - mu) * (v1.w - mu);
    for (int d = 1; d < 64; d <<= 1) s2 += __shfl_xor(s2, d);
    const float rs = rsqrtf(s2 * (1.0f / D_) + EPS_);
    float4 g0 = ((const float4*)g)[lane], g1v = ((const float4*)g)[lane + 64];
    float4 b0 = ((const float4*)be)[lane], b1v = ((const float4*)be)[lane + 64];
    float ov[8];
    ov[0] = (v0.x - mu) * rs * g0.x + b0.x;
    ov[1] = (v0.y - mu) * rs * g0.y + b0.y;
    ov[2] = (v0.z - mu) * rs * g0.z + b0.z;
    ov[3] = (v0.w - mu) * rs * g0.w + b0.w;
    ov[4] = (v1.x - mu) * rs * g1v.x + b1v.x;
    ov[5] = (v1.y - mu) * rs * g1v.y + b1v.y;
    ov[6] = (v1.z - mu) * rs * g1v.z + b1v.z;
    ov[7] = (v1.w - mu) * rs * g1v.w + b1v.w;
    u16x4 h0, l0, h1, l1;
#pragma unroll
    for (int j = 0; j < 4; ++j) {
        unsigned short hb = f2bf(ov[j]);
        h0[j] = hb; l0[j] = f2bf(ov[j] - bf2f(hb));
        unsigned short hb2 = f2bf(ov[4 + j]);
        h1[j] = hb2; l1[j] = f2bf(ov[4 + j] - bf2f(hb2));
    }
    ((u16x4*)(Yh + (size_t)row * D_))[lane] = h0;
    ((u16x4*)(Yh + (size_t)row * D_))[lane + 64] = h1;
    ((u16x4*)(Yl + (size_t)row * D_))[lane] = l0;
    ((u16x4*)(Yl + (size_t)row * D_))[lane + 64] = l1;
}

// =================================================================
// LN2: y = LayerNorm((xh+xl) + r) fp32 out
// =================================================================
__global__ __launch_bounds__(256)
void add_ln_out(const unsigned short* __restrict__ Xh, const unsigned short* __restrict__ Xl,
                const float* __restrict__ R, const float* __restrict__ g,
                const float* __restrict__ be, float* __restrict__ Y) {
    const int row = blockIdx.x * 4 + (threadIdx.x >> 6);
    const int lane = threadIdx.x & 63;
    u16x4 xh0 = ((const u16x4*)(Xh + (size_t)row * D_))[lane];
    u16x4 xh1 = ((const u16x4*)(Xh + (size_t)row * D_))[lane + 64];
    u16x4 xl0 = ((const u16x4*)(Xl + (size_t)row * D_))[lane];
    u16x4 xl1 = ((const u16x4*)(Xl + (size_t)row * D_))[lane + 64];
    const float4* rp = (const float4*)(R + (size_t)row * D_);
    float4 r0 = rp[lane], r1 = rp[lane + 64];
    float v[8];
    v[0] = bf2f(xh0.x) + bf2f(xl0.x) + r0.x;
    v[1] = bf2f(xh0.y) + bf2f(xl0.y) + r0.y;
    v[2] = bf2f(xh0.z) + bf2f(xl0.z) + r0.z;
    v[3] = bf2f(xh0.w) + bf2f(xl0.w) + r0.w;
    v[4] = bf2f(xh1.x) + bf2f(xl1.x) + r1.x;
    v[5] = bf2f(xh1.y) + bf2f(xl1.y) + r1.y;
    v[6] = bf2f(xh1.z) + bf2f(xl1.z) + r1.z;
    v[7] = bf2f(xh1.w) + bf2f(xl1.w) + r1.w;
    float sum = 0.f;
#pragma unroll
    for (int j = 0; j < 8; ++j) sum += v[j];
    for (int d = 1; d < 64; d <<= 1) sum += __shfl_xor(sum, d);
    const float mu = sum * (1.0f / D_);
    float s2 = 0.f;
#pragma unroll
    for (int j = 0; j < 8; ++j) s2 += (v[j] - mu) * (v[j] - mu);
    for (int d = 1; d < 64; d <<= 1) s2 += __shfl_xor(s2, d);
    const float rs = rsqrtf(s2 * (1.0f / D_) + EPS_);
    float4 g0 = ((const float4*)g)[lane], g1v = ((const float4*)g)[lane + 64];
    float4 b0 = ((const float4*)be)[lane], b1v = ((const float4*)be)[lane + 64];
    float4 o0, o1;
    o0.x = (v[0] - mu) * rs * g0.x + b0.x;
    o0.y = (v[1] - mu) * rs * g0.y + b0.y;
    o0.z = (v[2] - mu) * rs * g0.z + b0.z;
    o0.w = (v[3] - mu) * rs * g0.w + b0.w;
    o1.x = (v[4] - mu) * rs * g1v.x + b1v.x;
    o1.y = (v[5] - mu) * rs * g1v.y + b1v.y;
    o1.z = (v[6] - mu) * rs * g1v.z + b1v.z;
    o1.w = (v[7] - mu) * rs * g1v.w + b1v.w;
    ((float4*)(Y + (size_t)row * D_))[lane] = o0;
    ((float4*)(Y + (size_t)row * D_))[lane + 64] = o1;
}

// =================================================================
extern "C" void kernel_launch(void* const* d_in, const int* in_sizes, int n_in,
                              void* d_out, int out_size, void* d_ws, size_t ws_size,
                              hipStream_t stream) {
    const float* x   = (const float*)d_in[0];
    const float* wq  = (const float*)d_in[1];
    const float* bq  = (const float*)d_in[2];
    const float* wk  = (const float*)d_in[3];
    const float* bk  = (const float*)d_in[4];
    const float* wv  = (const float*)d_in[5];
    const float* bv  = (const float*)d_in[6];
    const float* wo  = (const float*)d_in[7];
    const float* bo  = (const float*)d_in[8];
    const float* w1  = (const float*)d_in[9];
    const float* b1  = (const float*)d_in[10];
    const float* w2  = (const float*)d_in[11];
    const float* b2  = (const float*)d_in[12];
    const float* g1  = (const float*)d_in[13];
    const float* be1 = (const float*)d_in[14];
    const float* g2  = (const float*)d_in[15];
    const float* be2 = (const float*)d_in[16];

    char* W = (char*)d_ws;
#define WSOFF(kb) ((char*)W + (size_t)(kb) * 1024)
    // packed QKV weights: hi rows [wq|wk|wv] then lo rows [wq|wk|wv]
    unsigned short* wqkvh = (unsigned short*)WSOFF(0);      // [1536][512]
    unsigned short* wqkvl = (unsigned short*)WSOFF(1536);   // [1536][512]
    unsigned short* wqh = wqkvh;                            // rows 0-511
    unsigned short* wkh = (unsigned short*)WSOFF(512);      // rows 512-1023
    unsigned short* wvh = (unsigned short*)WSOFF(1024);     // rows 1024-1535
    unsigned short* wql = wqkvl;
    unsigned short* wkl = (unsigned short*)WSOFF(2048);
    unsigned short* wvl = (unsigned short*)WSOFF(2560);
    unsigned short* woh = (unsigned short*)WSOFF(3072);
    unsigned short* wol = (unsigned short*)WSOFF(3584);
    unsigned short* w1h = (unsigned short*)WSOFF(4096);
    unsigned short* w1l = (unsigned short*)WSOFF(5120);
    unsigned short* w2h = (unsigned short*)WSOFF(6144);
    unsigned short* w2l = (unsigned short*)WSOFF(7168);
    unsigned short* xh  = (unsigned short*)WSOFF(8192);
    unsigned short* xl  = (unsigned short*)WSOFF(16384);
    unsigned short* qf  = (unsigned short*)WSOFF(24576);   // fp16 [B,H,S,64]
    unsigned short* kf  = (unsigned short*)WSOFF(32768);   // fp16 [B,H,S,64]
    unsigned short* vf  = (unsigned short*)WSOFF(40960);   // fp16 [B,H,S,64]
    unsigned short* avh = (unsigned short*)WSOFF(8192);    // reuse xh
    unsigned short* avl = (unsigned short*)WSOFF(16384);   // reuse xl
    float*          ao  = (float*)WSOFF(24576);            // reuse qf,kf (16MB)
    unsigned short* x1h = (unsigned short*)WSOFF(40960);   // reuse vf
    unsigned short* x1l = (unsigned short*)WSOFF(49152);
    unsigned short* hh  = (unsigned short*)WSOFF(8192);    // reuse avh/avl
    float*          ff  = (float*)WSOFF(24576);            // reuse ao

    const int M = B_ * S_;  // 8192
    dim3 blk(256);
    const unsigned short* NUS = nullptr;
    const float* NF = nullptr;

    split_f32<<<dim3(4096), blk, 0, stream>>>((const float4*)x, (u16x4*)xh, (u16x4*)xl, 1048576);
    split_f32<<<dim3(256), blk, 0, stream>>>((const float4*)wq, (u16x4*)wqh, (u16x4*)wql, 65536);
    split_f32<<<dim3(256), blk, 0, stream>>>((const float4*)wk, (u16x4*)wkh, (u16x4*)wkl, 65536);
    split_f32<<<dim3(256), blk, 0, stream>>>((const float4*)wv, (u16x4*)wvh, (u16x4*)wvl, 65536);
    split_f32<<<dim3(256), blk, 0, stream>>>((const float4*)wo, (u16x4*)woh, (u16x4*)wol, 65536);
    split_f32<<<dim3(512), blk, 0, stream>>>((const float4*)w1, (u16x4*)w1h, (u16x4*)w1l, 131072);
    split_f32<<<dim3(512), blk, 0, stream>>>((const float4*)w2, (u16x4*)w2h, (u16x4*)w2l, 131072);

    // fused QKV projection -> fp16 [B,H,S,HD] (q pre-scaled by 1/8)
    gemm_x3<6, true><<<dim3(64, 12), blk, 0, stream>>>(
        xh, xl, wqkvh, wqkvl, bq, bk, bv, 0.125f,
        nullptr, qf, kf, vf, M, 1536, D_);
    // MFMA flash attention
    attn_mfma<<<dim3(S_ / 64, B_ * H_), blk, 0, stream>>>(
        (const h16*)qf, (const h16*)kf, (const h16*)vf, avh, avl);
    // output projection -> ao fp32
    gemm_x3<0, true><<<dim3(64, 4), blk, 0, stream>>>(
        avh, avl, woh, wol, bo, NF, NF, 1.0f,
        ao, nullptr, nullptr, nullptr, M, D_, D_);
    add_ln_split<<<dim3(M / 4), blk, 0, stream>>>(x, ao, g1, be1, x1h, x1l);
    gemm_x3<1, true><<<dim3(64, 8), blk, 0, stream>>>(
        x1h, x1l, w1h, w1l, b1, NF, NF, 1.0f,
        nullptr, hh, nullptr, nullptr, M, DFF_, D_);
    gemm_x3<0, false><<<dim3(64, 4), blk, 0, stream>>>(
        hh, NUS, w2h, w2l, b2, NF, NF, 1.0f,
        ff, nullptr, nullptr, nullptr, M, D_, DFF_);
    add_ln_out<<<dim3(M / 4), blk, 0, stream>>>(x1h, x1l, ff, g2, be2, (float*)d_out);
}

// Round 10
// 302.421 us; speedup vs baseline: 3.8636x; 1.2424x over previous
//
#include <hip/hip_runtime.h>
#include <math.h>

#define B_ 4
#define S_ 2048
#define D_ 512
#define H_ 8
#define HD_ 64
#define DFF_ 1024
#define EPS_ 1e-5f

typedef _Float16 h16;
typedef __attribute__((ext_vector_type(4))) unsigned short u16x4;
typedef __attribute__((ext_vector_type(8))) unsigned short u16x8;
typedef __attribute__((ext_vector_type(8))) short s16x8;
typedef __attribute__((ext_vector_type(4))) float f32x4;

__device__ __forceinline__ unsigned short f2bf(float f) {
    union { float f; unsigned u; } a; a.f = f;
    unsigned r = a.u + 0x7fffu + ((a.u >> 16) & 1u);   // RNE
    return (unsigned short)(r >> 16);
}
__device__ __forceinline__ float bf2f(unsigned short u) {
    union { unsigned u; float f; } a; a.u = ((unsigned)u) << 16;
    return a.f;
}
__device__ __forceinline__ unsigned short f2h(float f) {
    h16 h = (h16)f;
    union { h16 h; unsigned short u; } a; a.h = h;
    return a.u;
}
__device__ __forceinline__ void mfma_bf16(f32x4& d, s16x8 a, s16x8 b) {
    asm("v_mfma_f32_16x16x32_bf16 %0, %1, %2, %0" : "+v"(d) : "v"(a), "v"(b));
}
__device__ __forceinline__ void mfma_f16(f32x4& d, s16x8 a, s16x8 b) {
    asm("v_mfma_f32_16x16x32_f16 %0, %1, %2, %0" : "+v"(d) : "v"(a), "v"(b));
}

#define GLOAD(gp, lp) __builtin_amdgcn_global_load_lds( \
    (const __attribute__((address_space(1))) unsigned int*)(gp), \
    (__attribute__((address_space(3))) unsigned int*)(lp), 16, 0, 0)

// =================================================================
// prep: one launch — x -> bf16 cast; 6 weights -> split bf16 hi/lo
// blocks: [0,4096) x | +256 wq | +256 wk | +256 wv | +256 wo
//         | +512 w1 | +512 w2
// =================================================================
__device__ __forceinline__ void split4(float4 v, u16x4& h, u16x4& l) {
    h.x = f2bf(v.x); l.x = f2bf(v.x - bf2f(h.x));
    h.y = f2bf(v.y); l.y = f2bf(v.y - bf2f(h.y));
    h.z = f2bf(v.z); l.z = f2bf(v.z - bf2f(h.z));
    h.w = f2bf(v.w); l.w = f2bf(v.w - bf2f(h.w));
}
__global__ __launch_bounds__(256)
void prep(const float4* __restrict__ x,
          const float4* __restrict__ wq, const float4* __restrict__ wk,
          const float4* __restrict__ wv, const float4* __restrict__ wo,
          const float4* __restrict__ w1, const float4* __restrict__ w2,
          u16x4* __restrict__ xh,
          u16x4* __restrict__ wqh, u16x4* __restrict__ wql,
          u16x4* __restrict__ wkh, u16x4* __restrict__ wkl,
          u16x4* __restrict__ wvh, u16x4* __restrict__ wvl,
          u16x4* __restrict__ woh, u16x4* __restrict__ wol,
          u16x4* __restrict__ w1h, u16x4* __restrict__ w1l,
          u16x4* __restrict__ w2h, u16x4* __restrict__ w2l) {
    int blk = blockIdx.x, tid = threadIdx.x;
    if (blk < 4096) {          // x: bf16 cast only
        int i = blk * 256 + tid;
        float4 v = x[i];
        u16x4 h;
        h.x = f2bf(v.x); h.y = f2bf(v.y); h.z = f2bf(v.z); h.w = f2bf(v.w);
        xh[i] = h;
        return;
    }
    blk -= 4096;
    const float4* src; u16x4 *oh, *ol;
    if (blk < 256)       { src = wq; oh = wqh; ol = wql; }
    else if (blk < 512)  { src = wk; oh = wkh; ol = wkl; blk -= 256; }
    else if (blk < 768)  { src = wv; oh = wvh; ol = wvl; blk -= 512; }
    else if (blk < 1024) { src = wo; oh = woh; ol = wol; blk -= 768; }
    else if (blk < 1536) { src = w1; oh = w1h; ol = w1l; blk -= 1024; }
    else                 { src = w2; oh = w2h; ol = w2l; blk -= 1536; }
    int i = blk * 256 + tid;
    u16x4 h, l;
    split4(src[i], h, l);
    oh[i] = h; ol[i] = l;
}

// =================================================================
// MFMA GEMM: C = epi(A @ (Wh+Wl)^T + bias), A single bf16 (2 MFMA).
// (ASPLIT=true 3-MFMA path retained but unused this round.)
// EPI 0: Cf fp32 [M,N]. EPI 1: relu -> Ch bf16 [M,N].
// EPI 6: fused QKV — N=1536; sel=gc>>9 -> Ch/Ch2/Ch3, bias/2/3;
//        q (sel 0) scaled by `scale`. fp16 scatter [B,H,S,HD].
// =================================================================
template<int EPI, bool ASPLIT>
__global__ __launch_bounds__(256)
void gemm_x3(const unsigned short* __restrict__ Ah, const unsigned short* __restrict__ Al,
             const unsigned short* __restrict__ Wh, const unsigned short* __restrict__ Wl,
             const float* __restrict__ bias, const float* __restrict__ bias2,
             const float* __restrict__ bias3, float scale,
             float* __restrict__ Cf, unsigned short* __restrict__ Ch,
             unsigned short* __restrict__ Ch2, unsigned short* __restrict__ Ch3,
             int M, int N, int K) {
    __shared__ __align__(16) unsigned short AhL[4096];
    __shared__ __align__(16) unsigned short AlL[ASPLIT ? 4096 : 8];
    __shared__ __align__(16) unsigned short WhL[4096];
    __shared__ __align__(16) unsigned short WlL[4096];
    const int tid = threadIdx.x;
    const int lane = tid & 63;
    const int wid = tid >> 6;
    const int wr = wid >> 1, wc = wid & 1;
    const int bm = blockIdx.x * 128, bn = blockIdx.y * 128;

    const int i0 = wid * 128 + lane, i1 = i0 + 64;
    const int r0 = i0 >> 2, r1 = i1 >> 2;
    const int s0 = (i0 & 3) ^ ((r0 >> 1) & 3);
    const int s1 = (i1 & 3) ^ ((r1 >> 1) & 3);
    const size_t a0 = (size_t)(bm + r0) * K + s0 * 8;
    const size_t a1 = (size_t)(bm + r1) * K + s1 * 8;
    const size_t w0 = (size_t)(bn + r0) * K + s0 * 8;
    const size_t w1 = (size_t)(bn + r1) * K + s1 * 8;
    const int lb0 = (wid * 2 + 0) * 512;
    const int lb1 = (wid * 2 + 1) * 512;

    f32x4 acc[4][4];
#pragma unroll
    for (int m = 0; m < 4; ++m)
#pragma unroll
        for (int n = 0; n < 4; ++n) acc[m][n] = f32x4{0.f, 0.f, 0.f, 0.f};

    const int fr = lane & 15, ks = lane >> 4;
    int offA[4], offW[4];
#pragma unroll
    for (int m = 0; m < 4; ++m) {
        int r = wr * 64 + m * 16 + fr;
        offA[m] = r * 32 + ((ks ^ ((r >> 1) & 3)) * 8);
    }
#pragma unroll
    for (int n = 0; n < 4; ++n) {
        int r = wc * 64 + n * 16 + fr;
        offW[n] = r * 32 + ((ks ^ ((r >> 1) & 3)) * 8);
    }

    for (int k0 = 0; k0 < K; k0 += 32) {
        __syncthreads();
        GLOAD(Ah + a0 + k0, AhL + lb0);
        GLOAD(Ah + a1 + k0, AhL + lb1);
        if (ASPLIT) {
            GLOAD(Al + a0 + k0, AlL + lb0);
            GLOAD(Al + a1 + k0, AlL + lb1);
        }
        GLOAD(Wh + w0 + k0, WhL + lb0);
        GLOAD(Wh + w1 + k0, WhL + lb1);
        GLOAD(Wl + w0 + k0, WlL + lb0);
        GLOAD(Wl + w1 + k0, WlL + lb1);
        __syncthreads();
        s16x8 fah[4], fal[4], fwh[4], fwl[4];
#pragma unroll
        for (int m = 0; m < 4; ++m) {
            fah[m] = *(const s16x8*)&AhL[offA[m]];
            if (ASPLIT) fal[m] = *(const s16x8*)&AlL[offA[m]];
        }
#pragma unroll
        for (int n = 0; n < 4; ++n) {
            fwh[n] = *(const s16x8*)&WhL[offW[n]];
            fwl[n] = *(const s16x8*)&WlL[offW[n]];
        }
#pragma unroll
        for (int m = 0; m < 4; ++m)
#pragma unroll
            for (int n = 0; n < 4; ++n) {
                mfma_bf16(acc[m][n], fah[m], fwh[n]);
                mfma_bf16(acc[m][n], fah[m], fwl[n]);
                if (ASPLIT) mfma_bf16(acc[m][n], fal[m], fwh[n]);
            }
    }

#pragma unroll
    for (int n = 0; n < 4; ++n) {
        int gc = bn + wc * 64 + n * 16 + fr;
        if (EPI == 6) {
            int sel = gc >> 9, cc = gc & 511;
            int he = cc >> 6, hd = cc & 63;
            float bz = (sel == 0 ? bias : (sel == 1 ? bias2 : bias3))[cc];
            unsigned short* Co = (sel == 0 ? Ch : (sel == 1 ? Ch2 : Ch3));
            float scl = (sel == 0) ? scale : 1.0f;
#pragma unroll
            for (int m = 0; m < 4; ++m) {
                int grb = bm + wr * 64 + m * 16 + ks * 4;
#pragma unroll
                for (int j = 0; j < 4; ++j) {
                    int gr = grb + j;
                    int bb = gr >> 11, ss = gr & (S_ - 1);
                    Co[((size_t)(bb * H_ + he) * S_ + ss) * HD_ + hd] =
                        f2h((acc[m][n][j] + bz) * scl);
                }
            }
        } else {
            float bz = bias[gc];
#pragma unroll
            for (int m = 0; m < 4; ++m) {
                int grb = bm + wr * 64 + m * 16 + ks * 4;
#pragma unroll
                for (int j = 0; j < 4; ++j) {
                    int gr = grb + j;
                    float val = acc[m][n][j] + bz;
                    if (EPI == 0) {
                        Cf[(size_t)gr * N + gc] = val;
                    } else {   // EPI 1
                        Ch[(size_t)gr * N + gc] = f2bf(fmaxf(val, 0.f));
                    }
                }
            }
        }
    }
}

// =================================================================
// MFMA flash attention (round 10):
//  + l-sum via mfma(P, ones) — replaces 16-step shfl sum reduce
//  + defer-max (THR=8): fast path skips max reduce AND rescale;
//    wave-uniform __all check, slow path seeds/updates m per row.
// V conflict-free shifted layout from round 9 retained.
// Output: single bf16 AV [B,S,D].
// =================================================================
__global__ __launch_bounds__(256)
void attn_mfma(const h16* __restrict__ Qg, const h16* __restrict__ Kg,
               const h16* __restrict__ Vg, unsigned short* __restrict__ AVh) {
    __shared__ __align__(16) unsigned short Ks[64 * 72];      // [key][hd], pad 8
    __shared__ __align__(16) unsigned short Vs[64 * 72];      // [hd][key shifted]
    __shared__ __align__(16) unsigned short Ps[4 * 16 * 72];  // per-wave [q][key]
    const int tid = threadIdx.x, lane = tid & 63, w = tid >> 6;
    const int qb = blockIdx.x, bh = blockIdx.y;
    const int b = bh >> 3, h = bh & 7;
    const int lr = lane & 15, lk = lane >> 4;
    const size_t base = (size_t)bh * S_ * HD_;

    s16x8 qf[2];
    {
        const h16* qp = Qg + base + (size_t)(qb * 64 + w * 16 + lr) * HD_ + lk * 8;
        qf[0] = *(const s16x8*)(qp);
        qf[1] = *(const s16x8*)(qp + 32);
    }
    s16x8 ones;
#pragma unroll
    for (int e = 0; e < 8; ++e) ones[e] = (short)0x3C00;   // fp16 1.0

    const int srow = tid >> 2;
    const int sc = (tid & 3) * 16;
    const int vcol = (srow + sc) & 63;

    float m_[4];
    f32x4 acc_o[4], acc_l;
#pragma unroll
    for (int j = 0; j < 4; ++j) m_[j] = -INFINITY;
#pragma unroll
    for (int n = 0; n < 4; ++n) acc_o[n] = f32x4{0.f, 0.f, 0.f, 0.f};
    acc_l = f32x4{0.f, 0.f, 0.f, 0.f};

    for (int kt = 0; kt < S_ / 64; ++kt) {
        const unsigned short* kp = (const unsigned short*)(Kg + base) +
                                   (size_t)(kt * 64 + srow) * HD_ + sc;
        const unsigned short* vp = (const unsigned short*)(Vg + base) +
                                   (size_t)(kt * 64 + srow) * HD_ + sc;
        u16x8 ka = *(const u16x8*)kp, kb = *(const u16x8*)(kp + 8);
        u16x8 va = *(const u16x8*)vp, vb = *(const u16x8*)(vp + 8);
        __syncthreads();
        *(u16x8*)&Ks[srow * 72 + sc] = ka;
        *(u16x8*)&Ks[srow * 72 + sc + 8] = kb;
#pragma unroll
        for (int e = 0; e < 8; ++e) {
            Vs[(sc + e) * 72 + vcol]     = va[e];
            Vs[(sc + 8 + e) * 72 + vcol] = vb[e];
        }
        __syncthreads();

        // ---- scores ----
        f32x4 acc_s[4];
#pragma unroll
        for (int n = 0; n < 4; ++n) acc_s[n] = f32x4{0.f, 0.f, 0.f, 0.f};
#pragma unroll
        for (int n = 0; n < 4; ++n) {
            int krow = n * 16 + lr;
#pragma unroll
            for (int kk = 0; kk < 2; ++kk) {
                s16x8 kf = *(const s16x8*)&Ks[krow * 72 + kk * 32 + lk * 8];
                mfma_f16(acc_s[n], qf[kk], kf);
            }
        }

        // ---- softmax: defer-max fast path ----
        unsigned short* pw = Ps + w * (16 * 72);
        float lm[4];
        bool ok = true;
#pragma unroll
        for (int j = 0; j < 4; ++j) {
            lm[j] = fmaxf(fmaxf(acc_s[0][j], acc_s[1][j]),
                          fmaxf(acc_s[2][j], acc_s[3][j]));
            ok = ok && (lm[j] <= m_[j] + 8.0f);
        }
        if (__all(ok)) {
            // fast: keep old m; P bounded by e^8, fp16-safe; no rescale
#pragma unroll
            for (int j = 0; j < 4; ++j) {
                int q = lk * 4 + j;
#pragma unroll
                for (int n = 0; n < 4; ++n)
                    pw[q * 72 + n * 16 + lr] = f2h(__expf(acc_s[n][j] - m_[j]));
            }
        } else {
            // slow: full row-max reduce, update m, rescale O and l
#pragma unroll
            for (int j = 0; j < 4; ++j) {
                float mloc = lm[j];
                for (int d = 1; d < 16; d <<= 1) mloc = fmaxf(mloc, __shfl_xor(mloc, d));
                float mc = fmaxf(m_[j], mloc);
                float al = (m_[j] == -INFINITY) ? 0.f : __expf(m_[j] - mc);
                int q = lk * 4 + j;
#pragma unroll
                for (int n = 0; n < 4; ++n)
                    pw[q * 72 + n * 16 + lr] = f2h(__expf(acc_s[n][j] - mc));
                m_[j] = mc;
#pragma unroll
                for (int n = 0; n < 4; ++n) acc_o[n][j] *= al;
                acc_l[j] *= al;
            }
        }

        __syncthreads();   // P writes -> P fragment reads

        // ---- PV + l-sum ----
        s16x8 pf[2];
#pragma unroll
        for (int kk = 0; kk < 2; ++kk)
            pf[kk] = *(const s16x8*)&pw[lr * 72 + kk * 32 + lk * 8];
        mfma_f16(acc_l, pf[0], ones);
        mfma_f16(acc_l, pf[1], ones);
#pragma unroll
        for (int n2 = 0; n2 < 4; ++n2) {
            int vrow = n2 * 16 + lr;
#pragma unroll
            for (int kk = 0; kk < 2; ++kk) {
                int cb = (kk * 32 + lk * 8 + n2 * 16) & 63;
                s16x8 vf = *(const s16x8*)&Vs[vrow * 72 + cb];
                mfma_f16(acc_o[n2], pf[kk], vf);
            }
        }
    }

    // epilogue: /l (from MFMA ones-sum), single-bf16 AV write
#pragma unroll
    for (int j = 0; j < 4; ++j) {
        float inv = 1.0f / acc_l[j];
        int srw = qb * 64 + w * 16 + lk * 4 + j;
        size_t rb = ((size_t)b * S_ + srw) * D_ + h * HD_;
#pragma unroll
        for (int n2 = 0; n2 < 4; ++n2)
            AVh[rb + n2 * 16 + lr] = f2bf(acc_o[n2][j] * inv);
    }
}

// =================================================================
// LN1: y = LayerNorm(x + r) -> single bf16
// =================================================================
__global__ __launch_bounds__(256)
void add_ln_bf16(const float* __restrict__ X, const float* __restrict__ R,
                 const float* __restrict__ g, const float* __restrict__ be,
                 unsigned short* __restrict__ Yh) {
    const int row = blockIdx.x * 4 + (threadIdx.x >> 6);
    const int lane = threadIdx.x & 63;
    const float4* xp = (const float4*)(X + (size_t)row * D_);
    const float4* rp = (const float4*)(R + (size_t)row * D_);
    float4 v0 = xp[lane], v1 = xp[lane + 64];
    float4 r0 = rp[lane], r1 = rp[lane + 64];
    v0.x += r0.x; v0.y += r0.y; v0.z += r0.z; v0.w += r0.w;
    v1.x += r1.x; v1.y += r1.y; v1.z += r1.z; v1.w += r1.w;
    float sum = v0.x + v0.y + v0.z + v0.w + v1.x + v1.y + v1.z + v1.w;
    for (int d = 1; d < 64; d <<= 1) sum += __shfl_xor(sum, d);
    const float mu = sum * (1.0f / D_);
    float s2 = (v0.x - mu) * (v0.x - mu) + (v0.y - mu) * (v0.y - mu) +
               (v0.z - mu) * (v0.z - mu) + (v0.w - mu) * (v0.w - mu) +
               (v1.x - mu) * (v1.x - mu) + (v1.y - mu) * (v1.y - mu) +
               (v1.z - mu) * (v1.z - mu) + (v1.w - mu) * (v1.w - mu);
    for (int d = 1; d < 64; d <<= 1) s2 += __shfl_xor(s2, d);
    const float rs = rsqrtf(s2 * (1.0f / D_) + EPS_);
    float4 g0 = ((const float4*)g)[lane], g1v = ((const float4*)g)[lane + 64];
    float4 b0 = ((const float4*)be)[lane], b1v = ((const float4*)be)[lane + 64];
    u16x4 h0, h1;
    h0.x = f2bf((v0.x - mu) * rs * g0.x + b0.x);
    h0.y = f2bf((v0.y - mu) * rs * g0.y + b0.y);
    h0.z = f2bf((v0.z - mu) * rs * g0.z + b0.z);
    h0.w = f2bf((v0.w - mu) * rs * g0.w + b0.w);
    h1.x = f2bf((v1.x - mu) * rs * g1v.x + b1v.x);
    h1.y = f2bf((v1.y - mu) * rs * g1v.y + b1v.y);
    h1.z = f2bf((v1.z - mu) * rs * g1v.z + b1v.z);
    h1.w = f2bf((v1.w - mu) * rs * g1v.w + b1v.w);
    ((u16x4*)(Yh + (size_t)row * D_))[lane] = h0;
    ((u16x4*)(Yh + (size_t)row * D_))[lane + 64] = h1;
}

// =================================================================
// LN2: y = LayerNorm(xh + r) fp32 out (xh single bf16)
// =================================================================
__global__ __launch_bounds__(256)
void add_ln_out(const unsigned short* __restrict__ Xh,
                const float* __restrict__ R, const float* __restrict__ g,
                const float* __restrict__ be, float* __restrict__ Y) {
    const int row = blockIdx.x * 4 + (threadIdx.x >> 6);
    const int lane = threadIdx.x & 63;
    u16x4 xh0 = ((const u16x4*)(Xh + (size_t)row * D_))[lane];
    u16x4 xh1 = ((const u16x4*)(Xh + (size_t)row * D_))[lane + 64];
    const float4* rp = (const float4*)(R + (size_t)row * D_);
    float4 r0 = rp[lane], r1 = rp[lane + 64];
    float v[8];
    v[0] = bf2f(xh0.x) + r0.x; v[1] = bf2f(xh0.y) + r0.y;
    v[2] = bf2f(xh0.z) + r0.z; v[3] = bf2f(xh0.w) + r0.w;
    v[4] = bf2f(xh1.x) + r1.x; v[5] = bf2f(xh1.y) + r1.y;
    v[6] = bf2f(xh1.z) + r1.z; v[7] = bf2f(xh1.w) + r1.w;
    float sum = 0.f;
#pragma unroll
    for (int j = 0; j < 8; ++j) sum += v[j];
    for (int d = 1; d < 64; d <<= 1) sum += __shfl_xor(sum, d);
    const float mu = sum * (1.0f / D_);
    float s2 = 0.f;
#pragma unroll
    for (int j = 0; j < 8; ++j) s2 += (v[j] - mu) * (v[j] - mu);
    for (int d = 1; d < 64; d <<= 1) s2 += __shfl_xor(s2, d);
    const float rs = rsqrtf(s2 * (1.0f / D_) + EPS_);
    float4 g0 = ((const float4*)g)[lane], g1v = ((const float4*)g)[lane + 64];
    float4 b0 = ((const float4*)be)[lane], b1v = ((const float4*)be)[lane + 64];
    float4 o0, o1;
    o0.x = (v[0] - mu) * rs * g0.x + b0.x;
    o0.y = (v[1] - mu) * rs * g0.y + b0.y;
    o0.z = (v[2] - mu) * rs * g0.z + b0.z;
    o0.w = (v[3] - mu) * rs * g0.w + b0.w;
    o1.x = (v[4] - mu) * rs * g1v.x + b1v.x;
    o1.y = (v[5] - mu) * rs * g1v.y + b1v.y;
    o1.z = (v[6] - mu) * rs * g1v.z + b1v.z;
    o1.w = (v[7] - mu) * rs * g1v.w + b1v.w;
    ((float4*)(Y + (size_t)row * D_))[lane] = o0;
    ((float4*)(Y + (size_t)row * D_))[lane + 64] = o1;
}

// =================================================================
extern "C" void kernel_launch(void* const* d_in, const int* in_sizes, int n_in,
                              void* d_out, int out_size, void* d_ws, size_t ws_size,
                              hipStream_t stream) {
    const float* x   = (const float*)d_in[0];
    const float* wq  = (const float*)d_in[1];
    const float* bq  = (const float*)d_in[2];
    const float* wk  = (const float*)d_in[3];
    const float* bk  = (const float*)d_in[4];
    const float* wv  = (const float*)d_in[5];
    const float* bv  = (const float*)d_in[6];
    const float* wo  = (const float*)d_in[7];
    const float* bo  = (const float*)d_in[8];
    const float* w1  = (const float*)d_in[9];
    const float* b1  = (const float*)d_in[10];
    const float* w2  = (const float*)d_in[11];
    const float* b2  = (const float*)d_in[12];
    const float* g1  = (const float*)d_in[13];
    const float* be1 = (const float*)d_in[14];
    const float* g2  = (const float*)d_in[15];
    const float* be2 = (const float*)d_in[16];

    char* W = (char*)d_ws;
#define WSOFF(kb) ((char*)W + (size_t)(kb) * 1024)
    // packed QKV weights: hi rows [wq|wk|wv] then lo rows [wq|wk|wv]
    unsigned short* wqkvh = (unsigned short*)WSOFF(0);      // [1536][512]
    unsigned short* wqkvl = (unsigned short*)WSOFF(1536);
    unsigned short* wqh = wqkvh;
    unsigned short* wkh = (unsigned short*)WSOFF(512);
    unsigned short* wvh = (unsigned short*)WSOFF(1024);
    unsigned short* wql = wqkvl;
    unsigned short* wkl = (unsigned short*)WSOFF(2048);
    unsigned short* wvl = (unsigned short*)WSOFF(2560);
    unsigned short* woh = (unsigned short*)WSOFF(3072);
    unsigned short* wol = (unsigned short*)WSOFF(3584);
    unsigned short* w1h = (unsigned short*)WSOFF(4096);
    unsigned short* w1l = (unsigned short*)WSOFF(5120);
    unsigned short* w2h = (unsigned short*)WSOFF(6144);
    unsigned short* w2l = (unsigned short*)WSOFF(7168);
    unsigned short* xh  = (unsigned short*)WSOFF(8192);    // bf16 [M,D]
    unsigned short* qf  = (unsigned short*)WSOFF(24576);   // fp16 [B,H,S,64]
    unsigned short* kf  = (unsigned short*)WSOFF(32768);
    unsigned short* vf  = (unsigned short*)WSOFF(40960);
    unsigned short* avh = (unsigned short*)WSOFF(8192);    // reuse xh
    float*          ao  = (float*)WSOFF(24576);            // reuse qf,kf
    unsigned short* x1h = (unsigned short*)WSOFF(40960);   // reuse vf
    unsigned short* hh  = (unsigned short*)WSOFF(8192);    // reuse avh (16MB)
    float*          ff  = (float*)WSOFF(24576);            // reuse ao

    const int M = B_ * S_;  // 8192
    dim3 blk(256);
    const unsigned short* NUS = nullptr;
    const float* NF = nullptr;

    // one prep launch: x cast + 6 weight splits
    prep<<<dim3(6144), blk, 0, stream>>>(
        (const float4*)x, (const float4*)wq, (const float4*)wk, (const float4*)wv,
        (const float4*)wo, (const float4*)w1, (const float4*)w2,
        (u16x4*)xh,
        (u16x4*)wqh, (u16x4*)wql, (u16x4*)wkh, (u16x4*)wkl,
        (u16x4*)wvh, (u16x4*)wvl, (u16x4*)woh, (u16x4*)wol,
        (u16x4*)w1h, (u16x4*)w1l, (u16x4*)w2h, (u16x4*)w2l);

    // fused QKV projection -> fp16 [B,H,S,HD] (q pre-scaled 1/8)
    gemm_x3<6, false><<<dim3(64, 12), blk, 0, stream>>>(
        xh, NUS, wqkvh, wqkvl, bq, bk, bv, 0.125f,
        nullptr, qf, kf, vf, M, 1536, D_);
    // MFMA flash attention
    attn_mfma<<<dim3(S_ / 64, B_ * H_), blk, 0, stream>>>(
        (const h16*)qf, (const h16*)kf, (const h16*)vf, avh);
    // output projection -> ao fp32
    gemm_x3<0, false><<<dim3(64, 4), blk, 0, stream>>>(
        avh, NUS, woh, wol, bo, NF, NF, 1.0f,
        ao, nullptr, nullptr, nullptr, M, D_, D_);
    add_ln_bf16<<<dim3(M / 4), blk, 0, stream>>>(x, ao, g1, be1, x1h);
    gemm_x3<1, false><<<dim3(64, 8), blk, 0, stream>>>(
        x1h, NUS, w1h, w1l, b1, NF, NF, 1.0f,
        nullptr, hh, nullptr, nullptr, M, DFF_, D_);
    gemm_x3<0, false><<<dim3(64, 4), blk, 0, stream>>>(
        hh, NUS, w2h, w2l, b2, NF, NF, 1.0f,
        ff, nullptr, nullptr, nullptr, M, D_, DFF_);
    add_ln_out<<<dim3(M / 4), blk, 0, stream>>>(x1h, ff, g2, be2, (float*)d_out);
}

// Round 12
// 274.231 us; speedup vs baseline: 4.2607x; 1.1028x over previous
//
#include <hip/hip_runtime.h>
#include <math.h>

#define B_ 4
#define S_ 2048
#define D_ 512
#define H_ 8
#define HD_ 64
#define DFF_ 1024
#define EPS_ 1e-5f

typedef _Float16 h16;
typedef __attribute__((ext_vector_type(4))) unsigned short u16x4;
typedef __attribute__((ext_vector_type(8))) unsigned short u16x8;
typedef __attribute__((ext_vector_type(8))) short s16x8;
typedef __attribute__((ext_vector_type(4))) float f32x4;

__device__ __forceinline__ unsigned short f2bf(float f) {
    union { float f; unsigned u; } a; a.f = f;
    unsigned r = a.u + 0x7fffu + ((a.u >> 16) & 1u);   // RNE
    return (unsigned short)(r >> 16);
}
__device__ __forceinline__ float bf2f(unsigned short u) {
    union { unsigned u; float f; } a; a.u = ((unsigned)u) << 16;
    return a.f;
}
__device__ __forceinline__ unsigned short f2h(float f) {
    h16 h = (h16)f;
    union { h16 h; unsigned short u; } a; a.h = h;
    return a.u;
}
__device__ __forceinline__ void mfma_bf16(f32x4& d, s16x8 a, s16x8 b) {
    asm("v_mfma_f32_16x16x32_bf16 %0, %1, %2, %0" : "+v"(d) : "v"(a), "v"(b));
}
__device__ __forceinline__ void mfma_f16(f32x4& d, s16x8 a, s16x8 b) {
    asm("v_mfma_f32_16x16x32_f16 %0, %1, %2, %0" : "+v"(d) : "v"(a), "v"(b));
}

#define GLOAD(gp, lp) __builtin_amdgcn_global_load_lds( \
    (const __attribute__((address_space(1))) unsigned int*)(gp), \
    (__attribute__((address_space(3))) unsigned int*)(lp), 16, 0, 0)

// =================================================================
// prep: one launch — cast x and all 6 weights to single bf16.
// blocks: [0,4096) x | +256 wq | +256 wk | +256 wv | +256 wo
//         | +512 w1 | +512 w2
// =================================================================
__global__ __launch_bounds__(256)
void prep(const float4* __restrict__ x,
          const float4* __restrict__ wq, const float4* __restrict__ wk,
          const float4* __restrict__ wv, const float4* __restrict__ wo,
          const float4* __restrict__ w1, const float4* __restrict__ w2,
          u16x4* __restrict__ xh,
          u16x4* __restrict__ wqh, u16x4* __restrict__ wkh,
          u16x4* __restrict__ wvh, u16x4* __restrict__ woh,
          u16x4* __restrict__ w1h, u16x4* __restrict__ w2h) {
    int blk = blockIdx.x, tid = threadIdx.x;
    const float4* src; u16x4* dst;
    if (blk < 4096)      { src = x;  dst = xh; }
    else if (blk < 4352) { src = wq; dst = wqh; blk -= 4096; }
    else if (blk < 4608) { src = wk; dst = wkh; blk -= 4352; }
    else if (blk < 4864) { src = wv; dst = wvh; blk -= 4608; }
    else if (blk < 5120) { src = wo; dst = woh; blk -= 4864; }
    else if (blk < 5632) { src = w1; dst = w1h; blk -= 5120; }
    else                 { src = w2; dst = w2h; blk -= 5632; }
    int i = blk * 256 + tid;
    float4 v = src[i];
    u16x4 h;
    h.x = f2bf(v.x); h.y = f2bf(v.y); h.z = f2bf(v.z); h.w = f2bf(v.w);
    dst[i] = h;
}

// =================================================================
// bf16 MFMA GEMM: C = epi(A @ W^T + bias), A and W single bf16.
// 128x128 tile, BK=32, 4 waves, 16 MFMA + 4 GLOADs per K-iter.
// EPI 0: Cf fp32 [M,N]. EPI 1: relu -> Ch bf16 [M,N].
// EPI 6: fused QKV — N=1536; sel=gc>>9 -> Ch/Ch2/Ch3, bias/2/3;
//        q (sel 0) scaled by `scale`. fp16 scatter [B,H,S,HD].
// =================================================================
template<int EPI>
__global__ __launch_bounds__(256)
void gemm_bf(const unsigned short* __restrict__ Ah,
             const unsigned short* __restrict__ Wh,
             const float* __restrict__ bias, const float* __restrict__ bias2,
             const float* __restrict__ bias3, float scale,
             float* __restrict__ Cf, unsigned short* __restrict__ Ch,
             unsigned short* __restrict__ Ch2, unsigned short* __restrict__ Ch3,
             int M, int N, int K) {
    __shared__ __align__(16) unsigned short AhL[4096];
    __shared__ __align__(16) unsigned short WhL[4096];
    const int tid = threadIdx.x;
    const int lane = tid & 63;
    const int wid = tid >> 6;
    const int wr = wid >> 1, wc = wid & 1;
    const int bm = blockIdx.x * 128, bn = blockIdx.y * 128;

    const int i0 = wid * 128 + lane, i1 = i0 + 64;
    const int r0 = i0 >> 2, r1 = i1 >> 2;
    const int s0 = (i0 & 3) ^ ((r0 >> 1) & 3);
    const int s1 = (i1 & 3) ^ ((r1 >> 1) & 3);
    const size_t a0 = (size_t)(bm + r0) * K + s0 * 8;
    const size_t a1 = (size_t)(bm + r1) * K + s1 * 8;
    const size_t w0 = (size_t)(bn + r0) * K + s0 * 8;
    const size_t w1 = (size_t)(bn + r1) * K + s1 * 8;
    const int lb0 = (wid * 2 + 0) * 512;
    const int lb1 = (wid * 2 + 1) * 512;

    f32x4 acc[4][4];
#pragma unroll
    for (int m = 0; m < 4; ++m)
#pragma unroll
        for (int n = 0; n < 4; ++n) acc[m][n] = f32x4{0.f, 0.f, 0.f, 0.f};

    const int fr = lane & 15, ks = lane >> 4;
    int offA[4], offW[4];
#pragma unroll
    for (int m = 0; m < 4; ++m) {
        int r = wr * 64 + m * 16 + fr;
        offA[m] = r * 32 + ((ks ^ ((r >> 1) & 3)) * 8);
    }
#pragma unroll
    for (int n = 0; n < 4; ++n) {
        int r = wc * 64 + n * 16 + fr;
        offW[n] = r * 32 + ((ks ^ ((r >> 1) & 3)) * 8);
    }

    for (int k0 = 0; k0 < K; k0 += 32) {
        __syncthreads();
        GLOAD(Ah + a0 + k0, AhL + lb0);
        GLOAD(Ah + a1 + k0, AhL + lb1);
        GLOAD(Wh + w0 + k0, WhL + lb0);
        GLOAD(Wh + w1 + k0, WhL + lb1);
        __syncthreads();
        s16x8 fah[4], fwh[4];
#pragma unroll
        for (int m = 0; m < 4; ++m) fah[m] = *(const s16x8*)&AhL[offA[m]];
#pragma unroll
        for (int n = 0; n < 4; ++n) fwh[n] = *(const s16x8*)&WhL[offW[n]];
#pragma unroll
        for (int m = 0; m < 4; ++m)
#pragma unroll
            for (int n = 0; n < 4; ++n)
                mfma_bf16(acc[m][n], fah[m], fwh[n]);
    }

#pragma unroll
    for (int n = 0; n < 4; ++n) {
        int gc = bn + wc * 64 + n * 16 + fr;
        if (EPI == 6) {
            int sel = gc >> 9, cc = gc & 511;
            int he = cc >> 6, hd = cc & 63;
            float bz = (sel == 0 ? bias : (sel == 1 ? bias2 : bias3))[cc];
            unsigned short* Co = (sel == 0 ? Ch : (sel == 1 ? Ch2 : Ch3));
            float scl = (sel == 0) ? scale : 1.0f;
#pragma unroll
            for (int m = 0; m < 4; ++m) {
                int grb = bm + wr * 64 + m * 16 + ks * 4;
#pragma unroll
                for (int j = 0; j < 4; ++j) {
                    int gr = grb + j;
                    int bb = gr >> 11, ss = gr & (S_ - 1);
                    Co[((size_t)(bb * H_ + he) * S_ + ss) * HD_ + hd] =
                        f2h((acc[m][n][j] + bz) * scl);
                }
            }
        } else {
            float bz = bias[gc];
#pragma unroll
            for (int m = 0; m < 4; ++m) {
                int grb = bm + wr * 64 + m * 16 + ks * 4;
#pragma unroll
                for (int j = 0; j < 4; ++j) {
                    int gr = grb + j;
                    float val = acc[m][n][j] + bz;
                    if (EPI == 0) {
                        Cf[(size_t)gr * N + gc] = val;
                    } else {   // EPI 1
                        Ch[(size_t)gr * N + gc] = f2bf(fmaxf(val, 0.f));
                    }
                }
            }
        }
    }
}

// =================================================================
// MFMA flash attention (unchanged from round 10):
// l-sum via mfma(P, ones); defer-max THR=8; shifted V layout.
// =================================================================
__global__ __launch_bounds__(256)
void attn_mfma(const h16* __restrict__ Qg, const h16* __restrict__ Kg,
               const h16* __restrict__ Vg, unsigned short* __restrict__ AVh) {
    __shared__ __align__(16) unsigned short Ks[64 * 72];      // [key][hd], pad 8
    __shared__ __align__(16) unsigned short Vs[64 * 72];      // [hd][key shifted]
    __shared__ __align__(16) unsigned short Ps[4 * 16 * 72];  // per-wave [q][key]
    const int tid = threadIdx.x, lane = tid & 63, w = tid >> 6;
    const int qb = blockIdx.x, bh = blockIdx.y;
    const int b = bh >> 3, h = bh & 7;
    const int lr = lane & 15, lk = lane >> 4;
    const size_t base = (size_t)bh * S_ * HD_;

    s16x8 qf[2];
    {
        const h16* qp = Qg + base + (size_t)(qb * 64 + w * 16 + lr) * HD_ + lk * 8;
        qf[0] = *(const s16x8*)(qp);
        qf[1] = *(const s16x8*)(qp + 32);
    }
    s16x8 ones;
#pragma unroll
    for (int e = 0; e < 8; ++e) ones[e] = (short)0x3C00;   // fp16 1.0

    const int srow = tid >> 2;
    const int sc = (tid & 3) * 16;
    const int vcol = (srow + sc) & 63;

    float m_[4];
    f32x4 acc_o[4], acc_l;
#pragma unroll
    for (int j = 0; j < 4; ++j) m_[j] = -INFINITY;
#pragma unroll
    for (int n = 0; n < 4; ++n) acc_o[n] = f32x4{0.f, 0.f, 0.f, 0.f};
    acc_l = f32x4{0.f, 0.f, 0.f, 0.f};

    for (int kt = 0; kt < S_ / 64; ++kt) {
        const unsigned short* kp = (const unsigned short*)(Kg + base) +
                                   (size_t)(kt * 64 + srow) * HD_ + sc;
        const unsigned short* vp = (const unsigned short*)(Vg + base) +
                                   (size_t)(kt * 64 + srow) * HD_ + sc;
        u16x8 ka = *(const u16x8*)kp, kb = *(const u16x8*)(kp + 8);
        u16x8 va = *(const u16x8*)vp, vb = *(const u16x8*)(vp + 8);
        __syncthreads();
        *(u16x8*)&Ks[srow * 72 + sc] = ka;
        *(u16x8*)&Ks[srow * 72 + sc + 8] = kb;
#pragma unroll
        for (int e = 0; e < 8; ++e) {
            Vs[(sc + e) * 72 + vcol]     = va[e];
            Vs[(sc + 8 + e) * 72 + vcol] = vb[e];
        }
        __syncthreads();

        // ---- scores ----
        f32x4 acc_s[4];
#pragma unroll
        for (int n = 0; n < 4; ++n) acc_s[n] = f32x4{0.f, 0.f, 0.f, 0.f};
#pragma unroll
        for (int n = 0; n < 4; ++n) {
            int krow = n * 16 + lr;
#pragma unroll
            for (int kk = 0; kk < 2; ++kk) {
                s16x8 kf = *(const s16x8*)&Ks[krow * 72 + kk * 32 + lk * 8];
                mfma_f16(acc_s[n], qf[kk], kf);
            }
        }

        // ---- softmax: defer-max fast path ----
        unsigned short* pw = Ps + w * (16 * 72);
        float lm[4];
        bool ok = true;
#pragma unroll
        for (int j = 0; j < 4; ++j) {
            lm[j] = fmaxf(fmaxf(acc_s[0][j], acc_s[1][j]),
                          fmaxf(acc_s[2][j], acc_s[3][j]));
            ok = ok && (lm[j] <= m_[j] + 8.0f);
        }
        if (__all(ok)) {
#pragma unroll
            for (int j = 0; j < 4; ++j) {
                int q = lk * 4 + j;
#pragma unroll
                for (int n = 0; n < 4; ++n)
                    pw[q * 72 + n * 16 + lr] = f2h(__expf(acc_s[n][j] - m_[j]));
            }
        } else {
#pragma unroll
            for (int j = 0; j < 4; ++j) {
                float mloc = lm[j];
                for (int d = 1; d < 16; d <<= 1) mloc = fmaxf(mloc, __shfl_xor(mloc, d));
                float mc = fmaxf(m_[j], mloc);
                float al = (m_[j] == -INFINITY) ? 0.f : __expf(m_[j] - mc);
                int q = lk * 4 + j;
#pragma unroll
                for (int n = 0; n < 4; ++n)
                    pw[q * 72 + n * 16 + lr] = f2h(__expf(acc_s[n][j] - mc));
                m_[j] = mc;
#pragma unroll
                for (int n = 0; n < 4; ++n) acc_o[n][j] *= al;
                acc_l[j] *= al;
            }
        }

        __syncthreads();   // P writes -> P fragment reads

        // ---- PV + l-sum ----
        s16x8 pf[2];
#pragma unroll
        for (int kk = 0; kk < 2; ++kk)
            pf[kk] = *(const s16x8*)&pw[lr * 72 + kk * 32 + lk * 8];
        mfma_f16(acc_l, pf[0], ones);
        mfma_f16(acc_l, pf[1], ones);
#pragma unroll
        for (int n2 = 0; n2 < 4; ++n2) {
            int vrow = n2 * 16 + lr;
#pragma unroll
            for (int kk = 0; kk < 2; ++kk) {
                int cb = (kk * 32 + lk * 8 + n2 * 16) & 63;
                s16x8 vf = *(const s16x8*)&Vs[vrow * 72 + cb];
                mfma_f16(acc_o[n2], pf[kk], vf);
            }
        }
    }

    // epilogue
#pragma unroll
    for (int j = 0; j < 4; ++j) {
        float inv = 1.0f / acc_l[j];
        int srw = qb * 64 + w * 16 + lk * 4 + j;
        size_t rb = ((size_t)b * S_ + srw) * D_ + h * HD_;
#pragma unroll
        for (int n2 = 0; n2 < 4; ++n2)
            AVh[rb + n2 * 16 + lr] = f2bf(acc_o[n2][j] * inv);
    }
}

// =================================================================
// LN1: y = LayerNorm(x + r) -> single bf16
// =================================================================
__global__ __launch_bounds__(256)
void add_ln_bf16(const float* __restrict__ X, const float* __restrict__ R,
                 const float* __restrict__ g, const float* __restrict__ be,
                 unsigned short* __restrict__ Yh) {
    const int row = blockIdx.x * 4 + (threadIdx.x >> 6);
    const int lane = threadIdx.x & 63;
    const float4* xp = (const float4*)(X + (size_t)row * D_);
    const float4* rp = (const float4*)(R + (size_t)row * D_);
    float4 v0 = xp[lane], v1 = xp[lane + 64];
    float4 r0 = rp[lane], r1 = rp[lane + 64];
    v0.x += r0.x; v0.y += r0.y; v0.z += r0.z; v0.w += r0.w;
    v1.x += r1.x; v1.y += r1.y; v1.z += r1.z; v1.w += r1.w;
    float sum = v0.x + v0.y + v0.z + v0.w + v1.x + v1.y + v1.z + v1.w;
    for (int d = 1; d < 64; d <<= 1) sum += __shfl_xor(sum, d);
    const float mu = sum * (1.0f / D_);
    float s2 = (v0.x - mu) * (v0.x - mu) + (v0.y - mu) * (v0.y - mu) +
               (v0.z - mu) * (v0.z - mu) + (v0.w - mu) * (v0.w - mu) +
               (v1.x - mu) * (v1.x - mu) + (v1.y - mu) * (v1.y - mu) +
               (v1.z - mu) * (v1.z - mu) + (v1.w - mu) * (v1.w - mu);
    for (int d = 1; d < 64; d <<= 1) s2 += __shfl_xor(s2, d);
    const float rs = rsqrtf(s2 * (1.0f / D_) + EPS_);
    float4 g0 = ((const float4*)g)[lane], g1v = ((const float4*)g)[lane + 64];
    float4 b0 = ((const float4*)be)[lane], b1v = ((const float4*)be)[lane + 64];
    u16x4 h0, h1;
    h0.x = f2bf((v0.x - mu) * rs * g0.x + b0.x);
    h0.y = f2bf((v0.y - mu) * rs * g0.y + b0.y);
    h0.z = f2bf((v0.z - mu) * rs * g0.z + b0.z);
    h0.w = f2bf((v0.w - mu) * rs * g0.w + b0.w);
    h1.x = f2bf((v1.x - mu) * rs * g1v.x + b1v.x);
    h1.y = f2bf((v1.y - mu) * rs * g1v.y + b1v.y);
    h1.z = f2bf((v1.z - mu) * rs * g1v.z + b1v.z);
    h1.w = f2bf((v1.w - mu) * rs * g1v.w + b1v.w);
    ((u16x4*)(Yh + (size_t)row * D_))[lane] = h0;
    ((u16x4*)(Yh + (size_t)row * D_))[lane + 64] = h1;
}

// =================================================================
// LN2: y = LayerNorm(xh + r) fp32 out (xh single bf16)
// =================================================================
__global__ __launch_bounds__(256)
void add_ln_out(const unsigned short* __restrict__ Xh,
                const float* __restrict__ R, const float* __restrict__ g,
                const float* __restrict__ be, float* __restrict__ Y) {
    const int row = blockIdx.x * 4 + (threadIdx.x >> 6);
    const int lane = threadIdx.x & 63;
    u16x4 xh0 = ((const u16x4*)(Xh + (size_t)row * D_))[lane];
    u16x4 xh1 = ((const u16x4*)(Xh + (size_t)row * D_))[lane + 64];
    const float4* rp = (const float4*)(R + (size_t)row * D_);
    float4 r0 = rp[lane], r1 = rp[lane + 64];
    float v[8];
    v[0] = bf2f(xh0.x) + r0.x; v[1] = bf2f(xh0.y) + r0.y;
    v[2] = bf2f(xh0.z) + r0.z; v[3] = bf2f(xh0.w) + r0.w;
    v[4] = bf2f(xh1.x) + r1.x; v[5] = bf2f(xh1.y) + r1.y;
    v[6] = bf2f(xh1.z) + r1.z; v[7] = bf2f(xh1.w) + r1.w;
    float sum = 0.f;
#pragma unroll
    for (int j = 0; j < 8; ++j) sum += v[j];
    for (int d = 1; d < 64; d <<= 1) sum += __shfl_xor(sum, d);
    const float mu = sum * (1.0f / D_);
    float s2 = 0.f;
#pragma unroll
    for (int j = 0; j < 8; ++j) s2 += (v[j] - mu) * (v[j] - mu);
    for (int d = 1; d < 64; d <<= 1) s2 += __shfl_xor(s2, d);
    const float rs = rsqrtf(s2 * (1.0f / D_) + EPS_);
    float4 g0 = ((const float4*)g)[lane], g1v = ((const float4*)g)[lane + 64];
    float4 b0 = ((const float4*)be)[lane], b1v = ((const float4*)be)[lane + 64];
    float4 o0, o1;
    o0.x = (v[0] - mu) * rs * g0.x + b0.x;
    o0.y = (v[1] - mu) * rs * g0.y + b0.y;
    o0.z = (v[2] - mu) * rs * g0.z + b0.z;
    o0.w = (v[3] - mu) * rs * g0.w + b0.w;
    o1.x = (v[4] - mu) * rs * g1v.x + b1v.x;
    o1.y = (v[5] - mu) * rs * g1v.y + b1v.y;
    o1.z = (v[6] - mu) * rs * g1v.z + b1v.z;
    o1.w = (v[7] - mu) * rs * g1v.w + b1v.w;
    ((float4*)(Y + (size_t)row * D_))[lane] = o0;
    ((float4*)(Y + (size_t)row * D_))[lane + 64] = o1;
}

// =================================================================
extern "C" void kernel_launch(void* const* d_in, const int* in_sizes, int n_in,
                              void* d_out, int out_size, void* d_ws, size_t ws_size,
                              hipStream_t stream) {
    const float* x   = (const float*)d_in[0];
    const float* wq  = (const float*)d_in[1];
    const float* bq  = (const float*)d_in[2];
    const float* wk  = (const float*)d_in[3];
    const float* bk  = (const float*)d_in[4];
    const float* wv  = (const float*)d_in[5];
    const float* bv  = (const float*)d_in[6];
    const float* wo  = (const float*)d_in[7];
    const float* bo  = (const float*)d_in[8];
    const float* w1  = (const float*)d_in[9];
    const float* b1  = (const float*)d_in[10];
    const float* w2  = (const float*)d_in[11];
    const float* b2  = (const float*)d_in[12];
    const float* g1  = (const float*)d_in[13];
    const float* be1 = (const float*)d_in[14];
    const float* g2  = (const float*)d_in[15];
    const float* be2 = (const float*)d_in[16];

    char* W = (char*)d_ws;
#define WSOFF(kb) ((char*)W + (size_t)(kb) * 1024)
    // packed QKV weights bf16: rows [wq|wk|wv] -> [1536][512]
    unsigned short* wqkvh = (unsigned short*)WSOFF(0);
    unsigned short* wqh = wqkvh;
    unsigned short* wkh = (unsigned short*)WSOFF(512);
    unsigned short* wvh = (unsigned short*)WSOFF(1024);
    unsigned short* woh = (unsigned short*)WSOFF(3072);
    unsigned short* w1h = (unsigned short*)WSOFF(4096);
    unsigned short* w2h = (unsigned short*)WSOFF(6144);
    unsigned short* xh  = (unsigned short*)WSOFF(8192);    // bf16 [M,D]
    unsigned short* qf  = (unsigned short*)WSOFF(24576);   // fp16 [B,H,S,64]
    unsigned short* kf  = (unsigned short*)WSOFF(32768);
    unsigned short* vf  = (unsigned short*)WSOFF(40960);
    unsigned short* avh = (unsigned short*)WSOFF(8192);    // reuse xh
    float*          ao  = (float*)WSOFF(24576);            // reuse qf,kf
    unsigned short* x1h = (unsigned short*)WSOFF(40960);   // reuse vf
    unsigned short* hh  = (unsigned short*)WSOFF(8192);    // reuse avh (16MB)
    float*          ff  = (float*)WSOFF(24576);            // reuse ao

    const int M = B_ * S_;  // 8192
    dim3 blk(256);
    const float* NF = nullptr;

    // one prep launch: cast x + 6 weights to bf16
    prep<<<dim3(6144), blk, 0, stream>>>(
        (const float4*)x, (const float4*)wq, (const float4*)wk, (const float4*)wv,
        (const float4*)wo, (const float4*)w1, (const float4*)w2,
        (u16x4*)xh, (u16x4*)wqh, (u16x4*)wkh, (u16x4*)wvh,
        (u16x4*)woh, (u16x4*)w1h, (u16x4*)w2h);

    // fused QKV projection -> fp16 [B,H,S,HD] (q pre-scaled 1/8)
    gemm_bf<6><<<dim3(64, 12), blk, 0, stream>>>(
        xh, wqkvh, bq, bk, bv, 0.125f,
        nullptr, qf, kf, vf, M, 1536, D_);
    // MFMA flash attention
    attn_mfma<<<dim3(S_ / 64, B_ * H_), blk, 0, stream>>>(
        (const h16*)qf, (const h16*)kf, (const h16*)vf, avh);
    // output projection -> ao fp32
    gemm_bf<0><<<dim3(64, 4), blk, 0, stream>>>(
        avh, woh, bo, NF, NF, 1.0f,
        ao, nullptr, nullptr, nullptr, M, D_, D_);
    add_ln_bf16<<<dim3(M / 4), blk, 0, stream>>>(x, ao, g1, be1, x1h);
    gemm_bf<1><<<dim3(64, 8), blk, 0, stream>>>(
        x1h, w1h, b1, NF, NF, 1.0f,
        nullptr, hh, nullptr, nullptr, M, DFF_, D_);
    gemm_bf<0><<<dim3(64, 4), blk, 0, stream>>>(
        hh, w2h, b2, NF, NF, 1.0f,
        ff, nullptr, nullptr, nullptr, M, D_, DFF_);
    add_ln_out<<<dim3(M / 4), blk, 0, stream>>>(x1h, ff, g2, be2, (float*)d_out);
}